// Round 2
// baseline (5051.014 us; speedup 1.0000x reference)
//
#include <hip/hip_runtime.h>
#include <hip/hip_bf16.h>
#include <math.h>

#define SEQ     4096
#define DMODEL  1024
#define DINNER  2048
#define DSTATE  16
#define DCONV   4
#define DTRANK  64
#define NH      8
#define PH      256
#define TOTOUT  4416
#define M       4096            // rows per batch (processed per-batch)

// ---- per-batch workspace layout (floats), reused for b=0 and b=1 ----
static const size_t OFF_Z   = 0;                                  // M*2048
static const size_t OFF_U   = OFF_Z   + (size_t)M * DINNER;       // M*2048 (pre-conv u)
static const size_t OFF_UC  = OFF_U   + (size_t)M * DINNER;       // M*2048 (conv out -> gated y -> g)
static const size_t OFF_DBC = OFF_UC  + (size_t)M * DINNER;       // M*320  (dt_h | B | C)
static const size_t OFF_DT  = OFF_DBC + (size_t)M * 320;          // M*8
static const size_t OFF_DA  = OFF_DT  + (size_t)M * NH;           // M*128
// total = 27,033,600 floats = 108.1 MB

#define TS 64
#define KT 16

// ---------------- in-projection GEMM with column-split outputs ----------------
// p_row = [ z(2048) | u(2048) | dt_h(64) | B(128) | C(128) ]
__global__ __launch_bounds__(256) void gemm_in(const float* __restrict__ A,
                                               const float* __restrict__ W,
                                               float* __restrict__ Z,
                                               float* __restrict__ U,
                                               float* __restrict__ DBC,
                                               int K) {
    __shared__ float As[KT][TS + 4];
    __shared__ float Ws[KT][TS + 4];
    const int tid = threadIdx.x;
    const int tx = tid % 16, ty = tid / 16;
    const int row0 = blockIdx.y * TS;
    const int col0 = blockIdx.x * TS;
    const int lk = tid % 16;
    const int lr = tid / 16;

    float acc[4][4] = {};
    for (int k0 = 0; k0 < K; k0 += KT) {
        #pragma unroll
        for (int i = 0; i < 4; i++) {
            int r = lr + i * 16;
            As[lk][r] = A[(size_t)(row0 + r) * K + k0 + lk];
            Ws[lk][r] = W[(size_t)(col0 + r) * K + k0 + lk];
        }
        __syncthreads();
        #pragma unroll
        for (int k = 0; k < KT; k++) {
            float a[4], b[4];
            #pragma unroll
            for (int i = 0; i < 4; i++) a[i] = As[k][ty * 4 + i];
            #pragma unroll
            for (int j = 0; j < 4; j++) b[j] = Ws[k][tx * 4 + j];
            #pragma unroll
            for (int i = 0; i < 4; i++)
                #pragma unroll
                for (int j = 0; j < 4; j++)
                    acc[i][j] = fmaf(a[i], b[j], acc[i][j]);
        }
        __syncthreads();
    }
    // column-split epilogue (block-uniform: 64 | all boundaries)
    float* Cb; int ldc, cl;
    if (col0 < DINNER)            { Cb = Z;   ldc = DINNER; cl = col0; }
    else if (col0 < 2 * DINNER)   { Cb = U;   ldc = DINNER; cl = col0 - DINNER; }
    else                          { Cb = DBC; ldc = 320;    cl = col0 - 2 * DINNER; }
    #pragma unroll
    for (int i = 0; i < 4; i++)
        #pragma unroll
        for (int j = 0; j < 4; j++)
            Cb[(size_t)(row0 + ty * 4 + i) * ldc + cl + tx * 4 + j] = acc[i][j];
}

// ---------------- generic fp32 GEMM: C[M,N] (+)= A[M,K] * W[N,K]^T ----------------
template<int ACC>
__global__ __launch_bounds__(256) void gemm_nt(const float* __restrict__ A,
                                               const float* __restrict__ W,
                                               float* __restrict__ C,
                                               int K, int ldc) {
    __shared__ float As[KT][TS + 4];
    __shared__ float Ws[KT][TS + 4];
    const int tid = threadIdx.x;
    const int tx = tid % 16, ty = tid / 16;
    const int row0 = blockIdx.y * TS;
    const int col0 = blockIdx.x * TS;
    const int lk = tid % 16;
    const int lr = tid / 16;

    float acc[4][4] = {};
    for (int k0 = 0; k0 < K; k0 += KT) {
        #pragma unroll
        for (int i = 0; i < 4; i++) {
            int r = lr + i * 16;
            As[lk][r] = A[(size_t)(row0 + r) * K + k0 + lk];
            Ws[lk][r] = W[(size_t)(col0 + r) * K + k0 + lk];
        }
        __syncthreads();
        #pragma unroll
        for (int k = 0; k < KT; k++) {
            float a[4], b[4];
            #pragma unroll
            for (int i = 0; i < 4; i++) a[i] = As[k][ty * 4 + i];
            #pragma unroll
            for (int j = 0; j < 4; j++) b[j] = Ws[k][tx * 4 + j];
            #pragma unroll
            for (int i = 0; i < 4; i++)
                #pragma unroll
                for (int j = 0; j < 4; j++)
                    acc[i][j] = fmaf(a[i], b[j], acc[i][j]);
        }
        __syncthreads();
    }
    #pragma unroll
    for (int i = 0; i < 4; i++)
        #pragma unroll
        for (int j = 0; j < 4; j++) {
            size_t idx = (size_t)(row0 + ty * 4 + i) * ldc + col0 + tx * 4 + j;
            C[idx] = ACC ? (C[idx] + acc[i][j]) : acc[i][j];
        }
}

// ---------------- causal depthwise conv (taps=4), per-batch ----------------
__global__ __launch_bounds__(256) void conv_dw(const float* __restrict__ U,
                                               const float* __restrict__ cw,
                                               const float* __restrict__ cb,
                                               float* __restrict__ UC) {
    int idx = blockIdx.x * blockDim.x + threadIdx.x;   // over M*DINNER
    int c = idx % DINNER;
    int t = idx / DINNER;
    float acc = cb[c];
    #pragma unroll
    for (int k = 0; k < DCONV; k++) {
        int tt = t + k - (DCONV - 1);
        if (tt >= 0)
            acc = fmaf(U[(size_t)tt * DINNER + c], cw[c * DCONV + k], acc);
    }
    UC[idx] = acc;
}

// ---------------- dt head + dA table, per-batch ----------------
__global__ __launch_bounds__(256) void dt_kernel(const float* __restrict__ DBC,
                                                 const float* __restrict__ W_dt,
                                                 const float* __restrict__ dt_bias,
                                                 const float* __restrict__ A_log,
                                                 float* __restrict__ dt,
                                                 float* __restrict__ dA) {
    int idx = blockIdx.x * blockDim.x + threadIdx.x;   // t*NH + h
    int h = idx % NH;
    int t = idx / NH;
    const float* row = DBC + (size_t)t * 320;          // dt_h at [0,64)
    float acc = dt_bias[h];
    #pragma unroll
    for (int r = 0; r < DTRANK; r++) acc = fmaf(row[r], W_dt[h * DTRANK + r], acc);
    float sp = acc > 20.f ? acc : log1pf(expf(acc));
    sp = fminf(fmaxf(sp, 1e-4f), 1.0f);
    dt[idx] = sp;
    #pragma unroll
    for (int n = 0; n < DSTATE; n++)
        dA[(size_t)idx * DSTATE + n] = expf(sp * (-expf(A_log[h * DSTATE + n])));
}

// ---------------- serial scan + skip + silu gating, in-place into UC ----------------
// one block per head; thread = p index. Writes gated y over UC (chunk staged first).
#define CH 16
__global__ __launch_bounds__(256) void scan_kernel(const float* __restrict__ Z,
                                                   float* __restrict__ UC,
                                                   const float* __restrict__ DBC,
                                                   const float* __restrict__ dt,
                                                   const float* __restrict__ dA,
                                                   const float* __restrict__ Dskip) {
    const int h = blockIdx.x;
    const int pidx = threadIdx.x;
    __shared__ float sdA[CH][DSTATE];
    __shared__ float sdB[CH][DSTATE];   // dt * B
    __shared__ float sC [CH][DSTATE];
    __shared__ float su [CH][PH];
    __shared__ float sz [CH][PH];

    float hst[DSTATE] = {};
    const float dsk = Dskip[h * PH + pidx];
    const int st = pidx >> 4, sn = pidx & 15;  // coeff staging: (t,n) pair

    for (int t0 = 0; t0 < M; t0 += CH) {
        { // coefficients: 256 threads cover 16t x 16n, scalar LDS stores
            size_t trow = (size_t)(t0 + st);
            float dtv = dt[trow * NH + h];
            sdA[st][sn] = dA[(trow * NH + h) * DSTATE + sn];
            sdB[st][sn] = dtv * DBC[trow * 320 + 64 + h * DSTATE + sn];
            sC [st][sn] =       DBC[trow * 320 + 192 + h * DSTATE + sn];
        }
        #pragma unroll 4
        for (int t = 0; t < CH; t++) {
            su[t][pidx] = UC[(size_t)(t0 + t) * DINNER + h * PH + pidx];
            sz[t][pidx] = Z [(size_t)(t0 + t) * DINNER + h * PH + pidx];
        }
        __syncthreads();

        for (int t = 0; t < CH; t++) {
            float u_p = su[t][pidx];
            float a0 = 0.f, a1 = 0.f, a2 = 0.f, a3 = 0.f;
            #pragma unroll
            for (int n = 0; n < 4; n++) {
                hst[n +  0] = fmaf(hst[n +  0], sdA[t][n +  0], u_p * sdB[t][n +  0]);
                hst[n +  4] = fmaf(hst[n +  4], sdA[t][n +  4], u_p * sdB[t][n +  4]);
                hst[n +  8] = fmaf(hst[n +  8], sdA[t][n +  8], u_p * sdB[t][n +  8]);
                hst[n + 12] = fmaf(hst[n + 12], sdA[t][n + 12], u_p * sdB[t][n + 12]);
                a0 = fmaf(hst[n +  0], sC[t][n +  0], a0);
                a1 = fmaf(hst[n +  4], sC[t][n +  4], a1);
                a2 = fmaf(hst[n +  8], sC[t][n +  8], a2);
                a3 = fmaf(hst[n + 12], sC[t][n + 12], a3);
            }
            float yv = ((a0 + a1) + (a2 + a3)) + dsk * u_p;
            float zv = sz[t][pidx];
            float sil = zv / (1.f + expf(-zv));
            UC[(size_t)(t0 + t) * DINNER + h * PH + pidx] = yv * sil;
        }
        __syncthreads();
    }
}

// ---------------- RMSNorm in place on UC ----------------
__global__ __launch_bounds__(256) void rmsnorm_kernel(float* __restrict__ G,
                                                      const float* __restrict__ norm_w) {
    const int t = blockIdx.x;
    float* row = G + (size_t)t * DINNER;
    float g[8];
    float ss = 0.f;
    #pragma unroll
    for (int i = 0; i < 8; i++) {
        int c = threadIdx.x + i * 256;
        g[i] = row[c];
        ss = fmaf(g[i], g[i], ss);
    }
    #pragma unroll
    for (int off = 32; off > 0; off >>= 1) ss += __shfl_down(ss, off);
    __shared__ float red[4];
    if ((threadIdx.x & 63) == 0) red[threadIdx.x >> 6] = ss;
    __syncthreads();
    float tot = red[0] + red[1] + red[2] + red[3];
    float inv = rsqrtf(tot / (float)DINNER + 1e-6f);
    #pragma unroll
    for (int i = 0; i < 8; i++) {
        int c = threadIdx.x + i * 256;
        row[c] = g[i] * inv * norm_w[c];
    }
}

extern "C" void kernel_launch(void* const* d_in, const int* in_sizes, int n_in,
                              void* d_out, int out_size, void* d_ws, size_t ws_size,
                              hipStream_t stream) {
    const float* x       = (const float*)d_in[0];
    const float* W_in    = (const float*)d_in[1];
    const float* W_dt    = (const float*)d_in[2];
    const float* conv_w  = (const float*)d_in[3];
    const float* conv_b  = (const float*)d_in[4];
    const float* A_log   = (const float*)d_in[5];
    const float* Dskip   = (const float*)d_in[6];
    const float* dt_bias = (const float*)d_in[7];
    const float* norm_w  = (const float*)d_in[8];
    const float* W_out   = (const float*)d_in[9];
    const float* W_res   = (const float*)d_in[10];
    float* out = (float*)d_out;
    float* ws  = (float*)d_ws;

    float* Z   = ws + OFF_Z;
    float* U   = ws + OFF_U;
    float* UC  = ws + OFF_UC;
    float* DBC = ws + OFF_DBC;
    float* dt  = ws + OFF_DT;
    float* dA  = ws + OFF_DA;

    for (int b = 0; b < 2; b++) {
        const float* xb = x + (size_t)b * M * DMODEL;
        float* outb = out + (size_t)b * M * DMODEL;

        // 1. in-projection (4096 x 4416 x 1024), split into Z | U | DBC
        gemm_in<<<dim3(TOTOUT / TS, M / TS), 256, 0, stream>>>(xb, W_in, Z, U, DBC, DMODEL);
        // 2. causal depthwise conv: U -> UC
        conv_dw<<<(M * DINNER) / 256, 256, 0, stream>>>(U, conv_w, conv_b, UC);
        // 3. dt head + dA table
        dt_kernel<<<(M * NH) / 256, 256, 0, stream>>>(DBC, W_dt, dt_bias, A_log, dt, dA);
        // 4. scan + Dskip + silu(z) gating, in-place on UC
        scan_kernel<<<NH, 256, 0, stream>>>(Z, UC, DBC, dt, dA, Dskip);
        // 5. residual GEMM accumulate: UC += x @ W_res^T  (4096 x 2048 x 1024)
        gemm_nt<1><<<dim3(DINNER / TS, M / TS), 256, 0, stream>>>(xb, W_res, UC, DMODEL, DINNER);
        // 6. RMSNorm in place
        rmsnorm_kernel<<<M, 256, 0, stream>>>(UC, norm_w);
        // 7. out-projection: out_b = UC @ W_out^T  (4096 x 1024 x 2048)
        gemm_nt<0><<<dim3(DMODEL / TS, M / TS), 256, 0, stream>>>(UC, W_out, outb, DINNER, DMODEL);
    }
}

// Round 3
// 2280.694 us; speedup vs baseline: 2.2147x; 2.2147x over previous
//
#include <hip/hip_runtime.h>
#include <hip/hip_bf16.h>
#include <math.h>

#define SEQ     4096
#define DMODEL  1024
#define DINNER  2048
#define DSTATE  16
#define DCONV   4
#define DTRANK  64
#define NH      8
#define PH      256
#define TOTOUT  4416
#define M       4096            // rows per batch (processed per-batch)
#define LC      64              // scan chunk length
#define NC      (M/LC)          // 64 chunks

// ---- per-batch workspace layout (floats), reused for b=0 and b=1 ----
static const size_t OFF_Z   = 0;                                  // M*2048
static const size_t OFF_U   = OFF_Z   + (size_t)M * DINNER;       // M*2048 (pre-conv u; dead after conv -> reused for hloc/Hent)
static const size_t OFF_UC  = OFF_U   + (size_t)M * DINNER;       // M*2048 (conv out -> gated y -> g)
static const size_t OFF_DBC = OFF_UC  + (size_t)M * DINNER;       // M*320  (dt_h | B | C)
static const size_t OFF_DT  = OFF_DBC + (size_t)M * 320;          // M*8
static const size_t OFF_DA  = OFF_DT  + (size_t)M * NH;           // M*128
static const size_t OFF_PC  = OFF_DA  + (size_t)M * NH * DSTATE;  // NC*NH*16 = 8K
// scan scratch aliased into dead U buffer:
//   hloc = U          (NC*NH*PH*16 = 2M floats, 8 MB)
//   Hent = U + 2M     (2M floats, 8 MB)

#define TS 64
#define KT 16

// ---------------- in-projection GEMM with column-split outputs ----------------
// p_row = [ z(2048) | u(2048) | dt_h(64) | B(128) | C(128) ]
__global__ __launch_bounds__(256) void gemm_in(const float* __restrict__ A,
                                               const float* __restrict__ W,
                                               float* __restrict__ Z,
                                               float* __restrict__ U,
                                               float* __restrict__ DBC,
                                               int K) {
    __shared__ float As[KT][TS + 4];
    __shared__ float Ws[KT][TS + 4];
    const int tid = threadIdx.x;
    const int tx = tid % 16, ty = tid / 16;
    const int row0 = blockIdx.y * TS;
    const int col0 = blockIdx.x * TS;
    const int lk = tid % 16;
    const int lr = tid / 16;

    float acc[4][4] = {};
    for (int k0 = 0; k0 < K; k0 += KT) {
        #pragma unroll
        for (int i = 0; i < 4; i++) {
            int r = lr + i * 16;
            As[lk][r] = A[(size_t)(row0 + r) * K + k0 + lk];
            Ws[lk][r] = W[(size_t)(col0 + r) * K + k0 + lk];
        }
        __syncthreads();
        #pragma unroll
        for (int k = 0; k < KT; k++) {
            float a[4], b[4];
            #pragma unroll
            for (int i = 0; i < 4; i++) a[i] = As[k][ty * 4 + i];
            #pragma unroll
            for (int j = 0; j < 4; j++) b[j] = Ws[k][tx * 4 + j];
            #pragma unroll
            for (int i = 0; i < 4; i++)
                #pragma unroll
                for (int j = 0; j < 4; j++)
                    acc[i][j] = fmaf(a[i], b[j], acc[i][j]);
        }
        __syncthreads();
    }
    float* Cb; int ldc, cl;
    if (col0 < DINNER)            { Cb = Z;   ldc = DINNER; cl = col0; }
    else if (col0 < 2 * DINNER)   { Cb = U;   ldc = DINNER; cl = col0 - DINNER; }
    else                          { Cb = DBC; ldc = 320;    cl = col0 - 2 * DINNER; }
    #pragma unroll
    for (int i = 0; i < 4; i++)
        #pragma unroll
        for (int j = 0; j < 4; j++)
            Cb[(size_t)(row0 + ty * 4 + i) * ldc + cl + tx * 4 + j] = acc[i][j];
}

// ---------------- generic fp32 GEMM: C[M,N] (+)= A[M,K] * W[N,K]^T ----------------
template<int ACC>
__global__ __launch_bounds__(256) void gemm_nt(const float* __restrict__ A,
                                               const float* __restrict__ W,
                                               float* __restrict__ C,
                                               int K, int ldc) {
    __shared__ float As[KT][TS + 4];
    __shared__ float Ws[KT][TS + 4];
    const int tid = threadIdx.x;
    const int tx = tid % 16, ty = tid / 16;
    const int row0 = blockIdx.y * TS;
    const int col0 = blockIdx.x * TS;
    const int lk = tid % 16;
    const int lr = tid / 16;

    float acc[4][4] = {};
    for (int k0 = 0; k0 < K; k0 += KT) {
        #pragma unroll
        for (int i = 0; i < 4; i++) {
            int r = lr + i * 16;
            As[lk][r] = A[(size_t)(row0 + r) * K + k0 + lk];
            Ws[lk][r] = W[(size_t)(col0 + r) * K + k0 + lk];
        }
        __syncthreads();
        #pragma unroll
        for (int k = 0; k < KT; k++) {
            float a[4], b[4];
            #pragma unroll
            for (int i = 0; i < 4; i++) a[i] = As[k][ty * 4 + i];
            #pragma unroll
            for (int j = 0; j < 4; j++) b[j] = Ws[k][tx * 4 + j];
            #pragma unroll
            for (int i = 0; i < 4; i++)
                #pragma unroll
                for (int j = 0; j < 4; j++)
                    acc[i][j] = fmaf(a[i], b[j], acc[i][j]);
        }
        __syncthreads();
    }
    #pragma unroll
    for (int i = 0; i < 4; i++)
        #pragma unroll
        for (int j = 0; j < 4; j++) {
            size_t idx = (size_t)(row0 + ty * 4 + i) * ldc + col0 + tx * 4 + j;
            C[idx] = ACC ? (C[idx] + acc[i][j]) : acc[i][j];
        }
}

// ---------------- causal depthwise conv (taps=4), per-batch ----------------
__global__ __launch_bounds__(256) void conv_dw(const float* __restrict__ U,
                                               const float* __restrict__ cw,
                                               const float* __restrict__ cb,
                                               float* __restrict__ UC) {
    int idx = blockIdx.x * blockDim.x + threadIdx.x;   // over M*DINNER
    int c = idx % DINNER;
    int t = idx / DINNER;
    float acc = cb[c];
    #pragma unroll
    for (int k = 0; k < DCONV; k++) {
        int tt = t + k - (DCONV - 1);
        if (tt >= 0)
            acc = fmaf(U[(size_t)tt * DINNER + c], cw[c * DCONV + k], acc);
    }
    UC[idx] = acc;
}

// ---------------- dt head + dA table, per-batch ----------------
__global__ __launch_bounds__(256) void dt_kernel(const float* __restrict__ DBC,
                                                 const float* __restrict__ W_dt,
                                                 const float* __restrict__ dt_bias,
                                                 const float* __restrict__ A_log,
                                                 float* __restrict__ dt,
                                                 float* __restrict__ dA) {
    int idx = blockIdx.x * blockDim.x + threadIdx.x;   // t*NH + h
    int h = idx % NH;
    int t = idx / NH;
    const float* row = DBC + (size_t)t * 320;          // dt_h at [0,64)
    float acc = dt_bias[h];
    #pragma unroll
    for (int r = 0; r < DTRANK; r++) acc = fmaf(row[r], W_dt[h * DTRANK + r], acc);
    float sp = acc > 20.f ? acc : log1pf(expf(acc));
    sp = fminf(fmaxf(sp, 1e-4f), 1.0f);
    dt[idx] = sp;
    #pragma unroll
    for (int n = 0; n < DSTATE; n++)
        dA[(size_t)idx * DSTATE + n] = expf(sp * (-expf(A_log[h * DSTATE + n])));
}

// ---------------- scan phase 1: per-chunk local end-state + decay product ----------------
__global__ __launch_bounds__(256) void scan_local(const float* __restrict__ UC,
                                                  const float* __restrict__ DBC,
                                                  const float* __restrict__ dt,
                                                  const float* __restrict__ dA,
                                                  float* __restrict__ hloc,
                                                  float* __restrict__ Pc) {
    const int c = blockIdx.x, h = blockIdx.y;
    const int pidx = threadIdx.x;
    __shared__ float sdA[LC][DSTATE];
    __shared__ float sdB[LC][DSTATE];   // dt * B
    const int st = pidx >> 4, sn = pidx & 15;
    #pragma unroll
    for (int j = 0; j < 4; j++) {
        int t = st + j * 16;
        size_t trow = (size_t)c * LC + t;
        float dtv = dt[trow * NH + h];
        sdA[t][sn] = dA[(trow * NH + h) * DSTATE + sn];
        sdB[t][sn] = dtv * DBC[trow * 320 + 64 + h * DSTATE + sn];
    }
    __syncthreads();

    float hst[DSTATE] = {};
    for (int t = 0; t < LC; t++) {
        float u_p = UC[((size_t)c * LC + t) * DINNER + h * PH + pidx];
        #pragma unroll
        for (int n = 0; n < DSTATE; n++)
            hst[n] = fmaf(hst[n], sdA[t][n], u_p * sdB[t][n]);
    }
    float* hl = hloc + (((size_t)c * NH + h) * PH + pidx) * DSTATE;
    #pragma unroll
    for (int n = 0; n < DSTATE; n++) hl[n] = hst[n];

    if (pidx < DSTATE) {
        float pr = 1.f;
        for (int t = 0; t < LC; t++) pr *= sdA[t][pidx];
        Pc[((size_t)c * NH + h) * DSTATE + pidx] = pr;
    }
}

// ---------------- scan phase 2: serial carry across chunks (exact) ----------------
__global__ __launch_bounds__(256) void scan_carry(const float* __restrict__ hloc,
                                                  const float* __restrict__ Pc,
                                                  float* __restrict__ Hent) {
    int g = blockIdx.x * 256 + threadIdx.x;   // 8*256*16 = 32768 threads
    int h = g >> 12;                          // (h, p*16+n)
    int inner = g & 4095;
    int n = g & 15;
    float carry = 0.f;
    for (int c = 0; c < NC; c++) {
        size_t idx = ((size_t)c * NH + h) * (PH * DSTATE) + inner;
        Hent[idx] = carry;
        carry = fmaf(Pc[((size_t)c * NH + h) * DSTATE + n], carry, hloc[idx]);
    }
}

// ---------------- scan phase 3: re-run chunk from entry state, gated output ----------------
__global__ __launch_bounds__(256) void scan_out(const float* __restrict__ Z,
                                                float* __restrict__ UC,
                                                const float* __restrict__ DBC,
                                                const float* __restrict__ dt,
                                                const float* __restrict__ dA,
                                                const float* __restrict__ Dskip,
                                                const float* __restrict__ Hent) {
    const int c = blockIdx.x, h = blockIdx.y;
    const int pidx = threadIdx.x;
    __shared__ float sdA[LC][DSTATE];
    __shared__ float sdB[LC][DSTATE];
    __shared__ float sC [LC][DSTATE];
    const int st = pidx >> 4, sn = pidx & 15;
    #pragma unroll
    for (int j = 0; j < 4; j++) {
        int t = st + j * 16;
        size_t trow = (size_t)c * LC + t;
        float dtv = dt[trow * NH + h];
        sdA[t][sn] = dA[(trow * NH + h) * DSTATE + sn];
        sdB[t][sn] = dtv * DBC[trow * 320 + 64 + h * DSTATE + sn];
        sC [t][sn] =       DBC[trow * 320 + 192 + h * DSTATE + sn];
    }
    __syncthreads();

    float hst[DSTATE];
    const float* he = Hent + (((size_t)c * NH + h) * PH + pidx) * DSTATE;
    #pragma unroll
    for (int n = 0; n < DSTATE; n++) hst[n] = he[n];
    const float dsk = Dskip[h * PH + pidx];

    for (int t = 0; t < LC; t++) {
        size_t off = ((size_t)c * LC + t) * DINNER + h * PH + pidx;
        float u_p = UC[off];
        float zv  = Z[off];
        float a0 = 0.f, a1 = 0.f, a2 = 0.f, a3 = 0.f;
        #pragma unroll
        for (int n = 0; n < 4; n++) {
            hst[n +  0] = fmaf(hst[n +  0], sdA[t][n +  0], u_p * sdB[t][n +  0]);
            hst[n +  4] = fmaf(hst[n +  4], sdA[t][n +  4], u_p * sdB[t][n +  4]);
            hst[n +  8] = fmaf(hst[n +  8], sdA[t][n +  8], u_p * sdB[t][n +  8]);
            hst[n + 12] = fmaf(hst[n + 12], sdA[t][n + 12], u_p * sdB[t][n + 12]);
            a0 = fmaf(hst[n +  0], sC[t][n +  0], a0);
            a1 = fmaf(hst[n +  4], sC[t][n +  4], a1);
            a2 = fmaf(hst[n +  8], sC[t][n +  8], a2);
            a3 = fmaf(hst[n + 12], sC[t][n + 12], a3);
        }
        float yv = ((a0 + a1) + (a2 + a3)) + dsk * u_p;
        float sil = zv / (1.f + expf(-zv));
        UC[off] = yv * sil;
    }
}

// ---------------- RMSNorm in place on UC ----------------
__global__ __launch_bounds__(256) void rmsnorm_kernel(float* __restrict__ G,
                                                      const float* __restrict__ norm_w) {
    const int t = blockIdx.x;
    float* row = G + (size_t)t * DINNER;
    float g[8];
    float ss = 0.f;
    #pragma unroll
    for (int i = 0; i < 8; i++) {
        int c = threadIdx.x + i * 256;
        g[i] = row[c];
        ss = fmaf(g[i], g[i], ss);
    }
    #pragma unroll
    for (int off = 32; off > 0; off >>= 1) ss += __shfl_down(ss, off);
    __shared__ float red[4];
    if ((threadIdx.x & 63) == 0) red[threadIdx.x >> 6] = ss;
    __syncthreads();
    float tot = red[0] + red[1] + red[2] + red[3];
    float inv = rsqrtf(tot / (float)DINNER + 1e-6f);
    #pragma unroll
    for (int i = 0; i < 8; i++) {
        int c = threadIdx.x + i * 256;
        row[c] = g[i] * inv * norm_w[c];
    }
}

extern "C" void kernel_launch(void* const* d_in, const int* in_sizes, int n_in,
                              void* d_out, int out_size, void* d_ws, size_t ws_size,
                              hipStream_t stream) {
    const float* x       = (const float*)d_in[0];
    const float* W_in    = (const float*)d_in[1];
    const float* W_dt    = (const float*)d_in[2];
    const float* conv_w  = (const float*)d_in[3];
    const float* conv_b  = (const float*)d_in[4];
    const float* A_log   = (const float*)d_in[5];
    const float* Dskip   = (const float*)d_in[6];
    const float* dt_bias = (const float*)d_in[7];
    const float* norm_w  = (const float*)d_in[8];
    const float* W_out   = (const float*)d_in[9];
    const float* W_res   = (const float*)d_in[10];
    float* out = (float*)d_out;
    float* ws  = (float*)d_ws;

    float* Z    = ws + OFF_Z;
    float* U    = ws + OFF_U;
    float* UC   = ws + OFF_UC;
    float* DBC  = ws + OFF_DBC;
    float* dt   = ws + OFF_DT;
    float* dA   = ws + OFF_DA;
    float* Pc   = ws + OFF_PC;
    float* hloc = U;                       // U is dead after conv_dw
    float* Hent = U + (size_t)NC * NH * PH * DSTATE;

    for (int b = 0; b < 2; b++) {
        const float* xb = x + (size_t)b * M * DMODEL;
        float* outb = out + (size_t)b * M * DMODEL;

        // 1. in-projection (4096 x 4416 x 1024), split into Z | U | DBC
        gemm_in<<<dim3(TOTOUT / TS, M / TS), 256, 0, stream>>>(xb, W_in, Z, U, DBC, DMODEL);
        // 2. causal depthwise conv: U -> UC  (U dead afterwards)
        conv_dw<<<(M * DINNER) / 256, 256, 0, stream>>>(U, conv_w, conv_b, UC);
        // 3. dt head + dA table
        dt_kernel<<<(M * NH) / 256, 256, 0, stream>>>(DBC, W_dt, dt_bias, A_log, dt, dA);
        // 4. chunk-parallel scan: local -> carry -> out (+Dskip + silu gating, in-place on UC)
        scan_local<<<dim3(NC, NH), 256, 0, stream>>>(UC, DBC, dt, dA, hloc, Pc);
        scan_carry<<<(NH * PH * DSTATE) / 256, 256, 0, stream>>>(hloc, Pc, Hent);
        scan_out<<<dim3(NC, NH), 256, 0, stream>>>(Z, UC, DBC, dt, dA, Dskip, Hent);
        // 5. residual GEMM accumulate: UC += x @ W_res^T  (4096 x 2048 x 1024)
        gemm_nt<1><<<dim3(DINNER / TS, M / TS), 256, 0, stream>>>(xb, W_res, UC, DMODEL, DINNER);
        // 6. RMSNorm in place
        rmsnorm_kernel<<<M, 256, 0, stream>>>(UC, norm_w);
        // 7. out-projection: out_b = UC @ W_out^T  (4096 x 1024 x 2048)
        gemm_nt<0><<<dim3(DMODEL / TS, M / TS), 256, 0, stream>>>(UC, W_out, outb, DINNER, DMODEL);
    }
}

// Round 4
// 636.438 us; speedup vs baseline: 7.9364x; 3.5835x over previous
//
#include <hip/hip_runtime.h>
#include <hip/hip_bf16.h>
#include <math.h>

#define SEQ     4096
#define DMODEL  1024
#define DINNER  2048
#define DSTATE  16
#define DCONV   4
#define DTRANK  64
#define NH      8
#define PH      256
#define TOTOUT  4416
#define M       4096            // rows per batch (processed per-batch)
#define LC      64              // scan chunk length
#define NC      (M/LC)          // 64 chunks

// ---- per-batch workspace layout (floats), reused for b=0 and b=1 (108 MB, proven safe) ----
static const size_t OFF_Z   = 0;                                  // M*2048
static const size_t OFF_U   = OFF_Z   + (size_t)M * DINNER;       // M*2048 (pre-conv u; dead after conv -> hloc/Hent)
static const size_t OFF_UC  = OFF_U   + (size_t)M * DINNER;       // M*2048 (conv out -> gated y -> g)
static const size_t OFF_DBC = OFF_UC  + (size_t)M * DINNER;       // M*320  (dt_h | B | C)
static const size_t OFF_DT  = OFF_DBC + (size_t)M * 320;          // M*8
static const size_t OFF_DA  = OFF_DT  + (size_t)M * NH;           // M*128
static const size_t OFF_PC  = OFF_DA  + (size_t)M * NH * DSTATE;  // NC*NH*16

typedef __attribute__((ext_vector_type(8))) short bf16x8;
typedef __attribute__((ext_vector_type(4))) float f32x4;

__device__ inline unsigned cvt2bf(float lo, float hi) {
    unsigned r;
    asm("v_cvt_pk_bf16_f32 %0, %1, %2" : "=v"(r) : "v"(lo), "v"(hi));
    return r;   // bits[15:0]=bf16(lo), bits[31:16]=bf16(hi) -> consecutive k order
}

// ================= bf16 MFMA GEMM =================
// C[M,N] (op)= A[M,K](fp32) x W[N,K](fp32)^T, computed in bf16 MFMA w/ fp32 accum.
// 128x128 tile, 4 waves (64x64 each), BK=32. Reg-staged fp32->bf16 into LDS.
// MODE 0: C0[row*ldc+col]  = acc
// MODE 1: C0[row*ldc+col] += acc
// MODE 2: in-proj split: Z=C0 (cols<2048), U=C1 (<4096), DBC=C2 (<4416, ldc 320)
template<int MODE>
__global__ __launch_bounds__(256) void gemm_bf(const float* __restrict__ A,
                                               const float* __restrict__ W,
                                               float* __restrict__ C0,
                                               float* __restrict__ C1,
                                               float* __restrict__ C2,
                                               int N, int K, int ldc) {
    __shared__ __align__(16) ushort Al[128 * 32];
    __shared__ __align__(16) ushort Bl[128 * 32];
    const int t    = threadIdx.x;
    const int lane = t & 63;
    const int w    = t >> 6;
    const int wr   = w >> 1, wc = w & 1;
    const int l15  = lane & 15, l4 = lane >> 4;
    const int row0 = blockIdx.y * 128;
    const int col0 = blockIdx.x * 128;

    // staging granules: granule g covers LDS elements [g*8, g*8+8) == row g>>2, k (g&3)*8..+8
    const int g0 = t, g1 = t + 256;
    const int ar0 = g0 >> 2, ak0 = (g0 & 3) * 8;
    const int ar1 = g1 >> 2, ak1 = (g1 & 3) * 8;
    const int wrow0 = col0 + ar0, wrow1 = col0 + ar1;

    const float4 fz = make_float4(0.f, 0.f, 0.f, 0.f);
    float4 a0, a1, a2, a3, b0, b1, b2, b3;

    // prologue loads (k0 = 0)
    {
        const float* s0 = A + (size_t)(row0 + ar0) * K + ak0;
        const float* s1 = A + (size_t)(row0 + ar1) * K + ak1;
        a0 = *(const float4*)s0; a1 = *(const float4*)(s0 + 4);
        a2 = *(const float4*)s1; a3 = *(const float4*)(s1 + 4);
        if (wrow0 < N) {
            const float* q0 = W + (size_t)wrow0 * K + ak0;
            b0 = *(const float4*)q0; b1 = *(const float4*)(q0 + 4);
        } else { b0 = fz; b1 = fz; }
        if (wrow1 < N) {
            const float* q1 = W + (size_t)wrow1 * K + ak1;
            b2 = *(const float4*)q1; b3 = *(const float4*)(q1 + 4);
        } else { b2 = fz; b3 = fz; }
    }

    f32x4 acc[4][4];
    #pragma unroll
    for (int i = 0; i < 4; i++)
        #pragma unroll
        for (int j = 0; j < 4; j++)
            acc[i][j] = (f32x4){0.f, 0.f, 0.f, 0.f};

    const bf16x8* Av = (const bf16x8*)Al;
    const bf16x8* Bv = (const bf16x8*)Bl;

    for (int k0 = 0; k0 < K; k0 += 32) {
        // convert staged regs -> LDS
        uint4 qa0, qa1, qb0, qb1;
        qa0.x = cvt2bf(a0.x, a0.y); qa0.y = cvt2bf(a0.z, a0.w);
        qa0.z = cvt2bf(a1.x, a1.y); qa0.w = cvt2bf(a1.z, a1.w);
        qa1.x = cvt2bf(a2.x, a2.y); qa1.y = cvt2bf(a2.z, a2.w);
        qa1.z = cvt2bf(a3.x, a3.y); qa1.w = cvt2bf(a3.z, a3.w);
        qb0.x = cvt2bf(b0.x, b0.y); qb0.y = cvt2bf(b0.z, b0.w);
        qb0.z = cvt2bf(b1.x, b1.y); qb0.w = cvt2bf(b1.z, b1.w);
        qb1.x = cvt2bf(b2.x, b2.y); qb1.y = cvt2bf(b2.z, b2.w);
        qb1.z = cvt2bf(b3.x, b3.y); qb1.w = cvt2bf(b3.z, b3.w);
        *(uint4*)&Al[g0 * 8] = qa0;
        *(uint4*)&Al[g1 * 8] = qa1;
        *(uint4*)&Bl[g0 * 8] = qb0;
        *(uint4*)&Bl[g1 * 8] = qb1;
        __syncthreads();

        // prefetch next K-tile while MFMAs run
        if (k0 + 32 < K) {
            const int kn = k0 + 32;
            const float* s0 = A + (size_t)(row0 + ar0) * K + kn + ak0;
            const float* s1 = A + (size_t)(row0 + ar1) * K + kn + ak1;
            a0 = *(const float4*)s0; a1 = *(const float4*)(s0 + 4);
            a2 = *(const float4*)s1; a3 = *(const float4*)(s1 + 4);
            if (wrow0 < N) {
                const float* q0 = W + (size_t)wrow0 * K + kn + ak0;
                b0 = *(const float4*)q0; b1 = *(const float4*)(q0 + 4);
            } else { b0 = fz; b1 = fz; }
            if (wrow1 < N) {
                const float* q1 = W + (size_t)wrow1 * K + kn + ak1;
                b2 = *(const float4*)q1; b3 = *(const float4*)(q1 + 4);
            } else { b2 = fz; b3 = fz; }
        }

        bf16x8 af[4], bw[4];
        #pragma unroll
        for (int mi = 0; mi < 4; mi++)
            af[mi] = Av[(wr * 64 + mi * 16 + l15) * 4 + l4];
        #pragma unroll
        for (int ni = 0; ni < 4; ni++)
            bw[ni] = Bv[(wc * 64 + ni * 16 + l15) * 4 + l4];
        #pragma unroll
        for (int mi = 0; mi < 4; mi++)
            #pragma unroll
            for (int ni = 0; ni < 4; ni++)
                acc[mi][ni] = __builtin_amdgcn_mfma_f32_16x16x32_bf16(af[mi], bw[ni], acc[mi][ni], 0, 0, 0);
        __syncthreads();
    }

    // epilogue: C/D layout col=lane&15, row=(lane>>4)*4+reg  [m89/m91]
    #pragma unroll
    for (int mi = 0; mi < 4; mi++) {
        #pragma unroll
        for (int ni = 0; ni < 4; ni++) {
            #pragma unroll
            for (int r = 0; r < 4; r++) {
                const int row = row0 + wr * 64 + mi * 16 + l4 * 4 + r;
                const int col = col0 + wc * 64 + ni * 16 + l15;
                const float v = acc[mi][ni][r];
                if (MODE == 0) {
                    C0[(size_t)row * ldc + col] = v;
                } else if (MODE == 1) {
                    C0[(size_t)row * ldc + col] += v;
                } else {
                    if (col0 < DINNER) {
                        C0[(size_t)row * DINNER + col] = v;
                    } else if (col0 < 2 * DINNER) {
                        C1[(size_t)row * DINNER + (col - DINNER)] = v;
                    } else {
                        if (col < TOTOUT)
                            C2[(size_t)row * 320 + (col - 2 * DINNER)] = v;
                    }
                }
            }
        }
    }
}

// ---------------- causal depthwise conv (taps=4), per-batch ----------------
__global__ __launch_bounds__(256) void conv_dw(const float* __restrict__ U,
                                               const float* __restrict__ cw,
                                               const float* __restrict__ cb,
                                               float* __restrict__ UC) {
    int idx = blockIdx.x * blockDim.x + threadIdx.x;   // over M*DINNER
    int c = idx % DINNER;
    int t = idx / DINNER;
    float acc = cb[c];
    #pragma unroll
    for (int k = 0; k < DCONV; k++) {
        int tt = t + k - (DCONV - 1);
        if (tt >= 0)
            acc = fmaf(U[(size_t)tt * DINNER + c], cw[c * DCONV + k], acc);
    }
    UC[idx] = acc;
}

// ---------------- dt head + dA table, per-batch ----------------
__global__ __launch_bounds__(256) void dt_kernel(const float* __restrict__ DBC,
                                                 const float* __restrict__ W_dt,
                                                 const float* __restrict__ dt_bias,
                                                 const float* __restrict__ A_log,
                                                 float* __restrict__ dt,
                                                 float* __restrict__ dA) {
    int idx = blockIdx.x * blockDim.x + threadIdx.x;   // t*NH + h
    int h = idx % NH;
    int t = idx / NH;
    const float* row = DBC + (size_t)t * 320;          // dt_h at [0,64)
    float acc = dt_bias[h];
    #pragma unroll
    for (int r = 0; r < DTRANK; r++) acc = fmaf(row[r], W_dt[h * DTRANK + r], acc);
    float sp = acc > 20.f ? acc : log1pf(expf(acc));
    sp = fminf(fmaxf(sp, 1e-4f), 1.0f);
    dt[idx] = sp;
    #pragma unroll
    for (int n = 0; n < DSTATE; n++)
        dA[(size_t)idx * DSTATE + n] = expf(sp * (-expf(A_log[h * DSTATE + n])));
}

// ---------------- scan phase 1: per-chunk local end-state + decay product ----------------
__global__ __launch_bounds__(256) void scan_local(const float* __restrict__ UC,
                                                  const float* __restrict__ DBC,
                                                  const float* __restrict__ dt,
                                                  const float* __restrict__ dA,
                                                  float* __restrict__ hloc,
                                                  float* __restrict__ Pc) {
    const int c = blockIdx.x, h = blockIdx.y;
    const int pidx = threadIdx.x;
    __shared__ float sdA[LC][DSTATE];
    __shared__ float sdB[LC][DSTATE];   // dt * B
    const int st = pidx >> 4, sn = pidx & 15;
    #pragma unroll
    for (int j = 0; j < 4; j++) {
        int t = st + j * 16;
        size_t trow = (size_t)c * LC + t;
        float dtv = dt[trow * NH + h];
        sdA[t][sn] = dA[(trow * NH + h) * DSTATE + sn];
        sdB[t][sn] = dtv * DBC[trow * 320 + 64 + h * DSTATE + sn];
    }
    __syncthreads();

    float hst[DSTATE] = {};
    for (int t = 0; t < LC; t++) {
        float u_p = UC[((size_t)c * LC + t) * DINNER + h * PH + pidx];
        #pragma unroll
        for (int n = 0; n < DSTATE; n++)
            hst[n] = fmaf(hst[n], sdA[t][n], u_p * sdB[t][n]);
    }
    float* hl = hloc + (((size_t)c * NH + h) * PH + pidx) * DSTATE;
    #pragma unroll
    for (int n = 0; n < DSTATE; n++) hl[n] = hst[n];

    if (pidx < DSTATE) {
        float pr = 1.f;
        for (int t = 0; t < LC; t++) pr *= sdA[t][pidx];
        Pc[((size_t)c * NH + h) * DSTATE + pidx] = pr;
    }
}

// ---------------- scan phase 2: serial carry across chunks (exact) ----------------
__global__ __launch_bounds__(256) void scan_carry(const float* __restrict__ hloc,
                                                  const float* __restrict__ Pc,
                                                  float* __restrict__ Hent) {
    int g = blockIdx.x * 256 + threadIdx.x;   // 32768 threads
    int h = g >> 12;
    int inner = g & 4095;
    int n = g & 15;
    float carry = 0.f;
    for (int c = 0; c < NC; c++) {
        size_t idx = ((size_t)c * NH + h) * (PH * DSTATE) + inner;
        Hent[idx] = carry;
        carry = fmaf(Pc[((size_t)c * NH + h) * DSTATE + n], carry, hloc[idx]);
    }
}

// ---------------- scan phase 3: re-run chunk from entry state, gated output ----------------
__global__ __launch_bounds__(256) void scan_out(const float* __restrict__ Z,
                                                float* __restrict__ UC,
                                                const float* __restrict__ DBC,
                                                const float* __restrict__ dt,
                                                const float* __restrict__ dA,
                                                const float* __restrict__ Dskip,
                                                const float* __restrict__ Hent) {
    const int c = blockIdx.x, h = blockIdx.y;
    const int pidx = threadIdx.x;
    __shared__ float sdA[LC][DSTATE];
    __shared__ float sdB[LC][DSTATE];
    __shared__ float sC [LC][DSTATE];
    const int st = pidx >> 4, sn = pidx & 15;
    #pragma unroll
    for (int j = 0; j < 4; j++) {
        int t = st + j * 16;
        size_t trow = (size_t)c * LC + t;
        float dtv = dt[trow * NH + h];
        sdA[t][sn] = dA[(trow * NH + h) * DSTATE + sn];
        sdB[t][sn] = dtv * DBC[trow * 320 + 64 + h * DSTATE + sn];
        sC [t][sn] =       DBC[trow * 320 + 192 + h * DSTATE + sn];
    }
    __syncthreads();

    float hst[DSTATE];
    const float* he = Hent + (((size_t)c * NH + h) * PH + pidx) * DSTATE;
    #pragma unroll
    for (int n = 0; n < DSTATE; n++) hst[n] = he[n];
    const float dsk = Dskip[h * PH + pidx];

    for (int t = 0; t < LC; t++) {
        size_t off = ((size_t)c * LC + t) * DINNER + h * PH + pidx;
        float u_p = UC[off];
        float zv  = Z[off];
        float a0 = 0.f, a1 = 0.f, a2 = 0.f, a3 = 0.f;
        #pragma unroll
        for (int n = 0; n < 4; n++) {
            hst[n +  0] = fmaf(hst[n +  0], sdA[t][n +  0], u_p * sdB[t][n +  0]);
            hst[n +  4] = fmaf(hst[n +  4], sdA[t][n +  4], u_p * sdB[t][n +  4]);
            hst[n +  8] = fmaf(hst[n +  8], sdA[t][n +  8], u_p * sdB[t][n +  8]);
            hst[n + 12] = fmaf(hst[n + 12], sdA[t][n + 12], u_p * sdB[t][n + 12]);
            a0 = fmaf(hst[n +  0], sC[t][n +  0], a0);
            a1 = fmaf(hst[n +  4], sC[t][n +  4], a1);
            a2 = fmaf(hst[n +  8], sC[t][n +  8], a2);
            a3 = fmaf(hst[n + 12], sC[t][n + 12], a3);
        }
        float yv = ((a0 + a1) + (a2 + a3)) + dsk * u_p;
        float sil = zv / (1.f + expf(-zv));
        UC[off] = yv * sil;
    }
}

// ---------------- RMSNorm in place on UC ----------------
__global__ __launch_bounds__(256) void rmsnorm_kernel(float* __restrict__ G,
                                                      const float* __restrict__ norm_w) {
    const int t = blockIdx.x;
    float* row = G + (size_t)t * DINNER;
    float g[8];
    float ss = 0.f;
    #pragma unroll
    for (int i = 0; i < 8; i++) {
        int c = threadIdx.x + i * 256;
        g[i] = row[c];
        ss = fmaf(g[i], g[i], ss);
    }
    #pragma unroll
    for (int off = 32; off > 0; off >>= 1) ss += __shfl_down(ss, off);
    __shared__ float red[4];
    if ((threadIdx.x & 63) == 0) red[threadIdx.x >> 6] = ss;
    __syncthreads();
    float tot = red[0] + red[1] + red[2] + red[3];
    float inv = rsqrtf(tot / (float)DINNER + 1e-6f);
    #pragma unroll
    for (int i = 0; i < 8; i++) {
        int c = threadIdx.x + i * 256;
        row[c] = g[i] * inv * norm_w[c];
    }
}

extern "C" void kernel_launch(void* const* d_in, const int* in_sizes, int n_in,
                              void* d_out, int out_size, void* d_ws, size_t ws_size,
                              hipStream_t stream) {
    const float* x       = (const float*)d_in[0];
    const float* W_in    = (const float*)d_in[1];
    const float* W_dt    = (const float*)d_in[2];
    const float* conv_w  = (const float*)d_in[3];
    const float* conv_b  = (const float*)d_in[4];
    const float* A_log   = (const float*)d_in[5];
    const float* Dskip   = (const float*)d_in[6];
    const float* dt_bias = (const float*)d_in[7];
    const float* norm_w  = (const float*)d_in[8];
    const float* W_out   = (const float*)d_in[9];
    const float* W_res   = (const float*)d_in[10];
    float* out = (float*)d_out;
    float* ws  = (float*)d_ws;

    float* Z    = ws + OFF_Z;
    float* U    = ws + OFF_U;
    float* UC   = ws + OFF_UC;
    float* DBC  = ws + OFF_DBC;
    float* dt   = ws + OFF_DT;
    float* dA   = ws + OFF_DA;
    float* Pc   = ws + OFF_PC;
    float* hloc = U;                       // U is dead after conv_dw
    float* Hent = U + (size_t)NC * NH * PH * DSTATE;

    for (int b = 0; b < 2; b++) {
        const float* xb = x + (size_t)b * M * DMODEL;
        float* outb = out + (size_t)b * M * DMODEL;

        // 1. in-projection (4096 x 4416 x 1024) bf16 MFMA, split into Z | U | DBC
        gemm_bf<2><<<dim3(35, 32), 256, 0, stream>>>(xb, W_in, Z, U, DBC, TOTOUT, DMODEL, 0);
        // 2. causal depthwise conv: U -> UC  (U dead afterwards)
        conv_dw<<<(M * DINNER) / 256, 256, 0, stream>>>(U, conv_w, conv_b, UC);
        // 3. dt head + dA table
        dt_kernel<<<(M * NH) / 256, 256, 0, stream>>>(DBC, W_dt, dt_bias, A_log, dt, dA);
        // 4. chunk-parallel scan: local -> carry -> out (+Dskip + silu gating, in-place on UC)
        scan_local<<<dim3(NC, NH), 256, 0, stream>>>(UC, DBC, dt, dA, hloc, Pc);
        scan_carry<<<(NH * PH * DSTATE) / 256, 256, 0, stream>>>(hloc, Pc, Hent);
        scan_out<<<dim3(NC, NH), 256, 0, stream>>>(Z, UC, DBC, dt, dA, Dskip, Hent);
        // 5. residual GEMM accumulate: UC += x @ W_res^T  (4096 x 2048 x 1024) bf16 MFMA
        gemm_bf<1><<<dim3(16, 32), 256, 0, stream>>>(xb, W_res, UC, nullptr, nullptr, DINNER, DMODEL, DINNER);
        // 6. RMSNorm in place
        rmsnorm_kernel<<<M, 256, 0, stream>>>(UC, norm_w);
        // 7. out-projection: out_b = UC @ W_out^T  (4096 x 1024 x 2048) bf16 MFMA
        gemm_bf<0><<<dim3(8, 32), 256, 0, stream>>>(UC, W_out, outb, nullptr, nullptr, DMODEL, DINNER, DMODEL);
    }
}

// Round 5
// 568.079 us; speedup vs baseline: 8.8914x; 1.1203x over previous
//
#include <hip/hip_runtime.h>
#include <hip/hip_bf16.h>
#include <math.h>

#define SEQ     4096
#define DMODEL  1024
#define DINNER  2048
#define DSTATE  16
#define DCONV   4
#define DTRANK  64
#define NH      8
#define PH      256
#define TOTOUT  4416
#define NPAD    4480            // TOTOUT padded to 128 multiple
#define M       4096            // rows per batch
#define LC      64              // scan chunk length
#define NC      (M/LC)          // 64 chunks

// ---- workspace layout (floats); ~134 MB ----
static const size_t OFF_Z    = 0;                                   // M*2048
static const size_t OFF_U    = (size_t)8*1024*1024;                 // M*2048 (dead after conv -> hloc/Hent/G_bf)
static const size_t OFF_UC   = (size_t)16*1024*1024;                // M*2048
static const size_t OFF_DBC  = (size_t)24*1024*1024;                // M*320
static const size_t OFF_DT   = OFF_DBC + (size_t)M*320;             // M*8
static const size_t OFF_DA   = OFF_DT  + (size_t)M*NH;              // M*128
static const size_t OFF_PC   = OFF_DA  + (size_t)M*NH*DSTATE;       // NC*NH*16 = 8192
static const size_t OFF_XBF  = OFF_PC  + (size_t)NC*NH*DSTATE;      // x_bf: M*1024 bf16 = 2M floats
static const size_t OFF_WIN  = OFF_XBF + (size_t)M*DMODEL/2;        // W_in_bf: 4480*1024 bf16
static const size_t OFF_WRES = OFF_WIN + (size_t)NPAD*DMODEL/2;     // W_res_bf: 2048*1024 bf16
static const size_t OFF_WOUT = OFF_WRES+ (size_t)DINNER*DMODEL/2;   // W_out_bf: 1024*2048 bf16

typedef __attribute__((ext_vector_type(8))) short bf16x8;
typedef __attribute__((ext_vector_type(4))) float f32x4;

__device__ inline unsigned cvt2bf(float lo, float hi) {
    unsigned r;
    asm("v_cvt_pk_bf16_f32 %0, %1, %2" : "=v"(r) : "v"(lo), "v"(hi));
    return r;
}

__device__ inline void gload16(const ushort* g, ushort* l) {
    __builtin_amdgcn_global_load_lds((const __attribute__((address_space(1))) unsigned*)(const void*)g,
                                     (__attribute__((address_space(3))) unsigned*)(void*)l, 16, 0, 0);
}

// ---------------- fp32 -> bf16 convert (+ zero pad region) ----------------
__global__ __launch_bounds__(256) void cvt_bf(const float* __restrict__ s,
                                              ushort* __restrict__ d, int nsrc) {
    int i = (blockIdx.x * 256 + threadIdx.x) * 8;
    float4 v0, v1;
    if (i + 8 <= nsrc) {
        v0 = *(const float4*)(s + i);
        v1 = *(const float4*)(s + i + 4);
    } else {
        v0 = make_float4(0.f, 0.f, 0.f, 0.f);
        v1 = v0;
    }
    uint4 o;
    o.x = cvt2bf(v0.x, v0.y); o.y = cvt2bf(v0.z, v0.w);
    o.z = cvt2bf(v1.x, v1.y); o.w = cvt2bf(v1.z, v1.w);
    *(uint4*)(d + i) = o;
}

// ================= bf16 MFMA GEMM, m97 structure =================
// C[M,N] (op)= A[Mrows x K]bf16 x W[Nrows x K]bf16^T; 128x128 tile, BK=32,
// 4 waves (64x64 each), global_load_lds width-16 staging, 2-barrier K-loop.
// MODE 0: C0 = acc ; MODE 1: C0 += acc ; MODE 2: split Z|U|DBC epilogue.
template<int MODE>
__global__ __launch_bounds__(256) void gemm_bf16(const ushort* __restrict__ A,
                                                 const ushort* __restrict__ W,
                                                 float* __restrict__ C0,
                                                 float* __restrict__ C1,
                                                 float* __restrict__ C2,
                                                 int ntx, int K, int ldc) {
    __shared__ __align__(16) ushort Al[128 * 32];
    __shared__ __align__(16) ushort Bl[128 * 32];
    const int nwg  = gridDim.x;
    const int orig = blockIdx.x;
    const int swz  = (orig & 7) * (nwg >> 3) + (orig >> 3);   // bijective: nwg % 8 == 0
    const int bx = swz % ntx, by = swz / ntx;
    const int row0 = by * 128, col0 = bx * 128;

    const int t    = threadIdx.x;
    const int lane = t & 63, w = t >> 6;
    const int wr   = w >> 1, wc = w & 1;
    const int l15  = lane & 15, l4 = lane >> 4;

    // staging granule: g = t covers LDS elems [g*8, g*8+8) = row g>>2, k (g&3)*8
    const int gr = t >> 2, gk = (t & 3) * 8;
    const ushort* Ag  = A + (size_t)(row0 + gr) * K + gk;
    const ushort* Ag2 = Ag + (size_t)64 * K;
    const ushort* Wg  = W + (size_t)(col0 + gr) * K + gk;
    const ushort* Wg2 = Wg + (size_t)64 * K;
    ushort* la  = &Al[t * 8];
    ushort* la2 = &Al[2048 + t * 8];
    ushort* lb  = &Bl[t * 8];
    ushort* lb2 = &Bl[2048 + t * 8];

    f32x4 acc[4][4];
    #pragma unroll
    for (int i = 0; i < 4; i++)
        #pragma unroll
        for (int j = 0; j < 4; j++)
            acc[i][j] = (f32x4){0.f, 0.f, 0.f, 0.f};

    const bf16x8* Av = (const bf16x8*)Al;
    const bf16x8* Bv = (const bf16x8*)Bl;

    for (int k0 = 0; k0 < K; k0 += 32) {
        gload16(Ag + k0, la);
        gload16(Ag2 + k0, la2);
        gload16(Wg + k0, lb);
        gload16(Wg2 + k0, lb2);
        __syncthreads();

        bf16x8 af[4], bw[4];
        #pragma unroll
        for (int mi = 0; mi < 4; mi++)
            af[mi] = Av[(wr * 64 + mi * 16 + l15) * 4 + l4];
        #pragma unroll
        for (int ni = 0; ni < 4; ni++)
            bw[ni] = Bv[(wc * 64 + ni * 16 + l15) * 4 + l4];
        #pragma unroll
        for (int mi = 0; mi < 4; mi++)
            #pragma unroll
            for (int ni = 0; ni < 4; ni++)
                acc[mi][ni] = __builtin_amdgcn_mfma_f32_16x16x32_bf16(af[mi], bw[ni], acc[mi][ni], 0, 0, 0);
        __syncthreads();
    }

    // epilogue: C/D layout col=lane&15, row=(lane>>4)*4+reg  [m89/m91]
    #pragma unroll
    for (int mi = 0; mi < 4; mi++) {
        #pragma unroll
        for (int ni = 0; ni < 4; ni++) {
            #pragma unroll
            for (int r = 0; r < 4; r++) {
                const int row = row0 + wr * 64 + mi * 16 + l4 * 4 + r;
                const int col = col0 + wc * 64 + ni * 16 + l15;
                const float v = acc[mi][ni][r];
                if (MODE == 0) {
                    C0[(size_t)row * ldc + col] = v;
                } else if (MODE == 1) {
                    C0[(size_t)row * ldc + col] += v;
                } else {
                    if (col0 < DINNER) {
                        C0[(size_t)row * DINNER + col] = v;
                    } else if (col0 < 2 * DINNER) {
                        C1[(size_t)row * DINNER + (col - DINNER)] = v;
                    } else if (col < TOTOUT) {
                        C2[(size_t)row * 320 + (col - 2 * DINNER)] = v;
                    }
                }
            }
        }
    }
}

// ---------------- causal depthwise conv (taps=4), per-batch ----------------
__global__ __launch_bounds__(256) void conv_dw(const float* __restrict__ U,
                                               const float* __restrict__ cw,
                                               const float* __restrict__ cb,
                                               float* __restrict__ UC) {
    int idx = blockIdx.x * blockDim.x + threadIdx.x;
    int c = idx % DINNER;
    int t = idx / DINNER;
    float acc = cb[c];
    #pragma unroll
    for (int k = 0; k < DCONV; k++) {
        int tt = t + k - (DCONV - 1);
        if (tt >= 0)
            acc = fmaf(U[(size_t)tt * DINNER + c], cw[c * DCONV + k], acc);
    }
    UC[idx] = acc;
}

// ---------------- dt head + dA table, per-batch ----------------
__global__ __launch_bounds__(256) void dt_kernel(const float* __restrict__ DBC,
                                                 const float* __restrict__ W_dt,
                                                 const float* __restrict__ dt_bias,
                                                 const float* __restrict__ A_log,
                                                 float* __restrict__ dt,
                                                 float* __restrict__ dA) {
    int idx = blockIdx.x * blockDim.x + threadIdx.x;
    int h = idx % NH;
    int t = idx / NH;
    const float* row = DBC + (size_t)t * 320;
    float acc = dt_bias[h];
    #pragma unroll
    for (int r = 0; r < DTRANK; r++) acc = fmaf(row[r], W_dt[h * DTRANK + r], acc);
    float sp = acc > 20.f ? acc : log1pf(expf(acc));
    sp = fminf(fmaxf(sp, 1e-4f), 1.0f);
    dt[idx] = sp;
    #pragma unroll
    for (int n = 0; n < DSTATE; n++)
        dA[(size_t)idx * DSTATE + n] = expf(sp * (-expf(A_log[h * DSTATE + n])));
}

// ---------------- scan phase 1: per-chunk local end-state + decay product ----------------
__global__ __launch_bounds__(256) void scan_local(const float* __restrict__ UC,
                                                  const float* __restrict__ DBC,
                                                  const float* __restrict__ dt,
                                                  const float* __restrict__ dA,
                                                  float* __restrict__ hloc,
                                                  float* __restrict__ Pc) {
    const int c = blockIdx.x, h = blockIdx.y;
    const int pidx = threadIdx.x;
    __shared__ float sdA[LC][DSTATE];
    __shared__ float sdB[LC][DSTATE];
    const int st = pidx >> 4, sn = pidx & 15;
    #pragma unroll
    for (int j = 0; j < 4; j++) {
        int t = st + j * 16;
        size_t trow = (size_t)c * LC + t;
        float dtv = dt[trow * NH + h];
        sdA[t][sn] = dA[(trow * NH + h) * DSTATE + sn];
        sdB[t][sn] = dtv * DBC[trow * 320 + 64 + h * DSTATE + sn];
    }
    __syncthreads();

    float hst[DSTATE] = {};
    for (int t = 0; t < LC; t++) {
        float u_p = UC[((size_t)c * LC + t) * DINNER + h * PH + pidx];
        #pragma unroll
        for (int n = 0; n < DSTATE; n++)
            hst[n] = fmaf(hst[n], sdA[t][n], u_p * sdB[t][n]);
    }
    float* hl = hloc + (((size_t)c * NH + h) * PH + pidx) * DSTATE;
    #pragma unroll
    for (int n = 0; n < DSTATE; n++) hl[n] = hst[n];

    if (pidx < DSTATE) {
        float pr = 1.f;
        for (int t = 0; t < LC; t++) pr *= sdA[t][pidx];
        Pc[((size_t)c * NH + h) * DSTATE + pidx] = pr;
    }
}

// ---------------- scan phase 2: serial carry across chunks ----------------
__global__ __launch_bounds__(256) void scan_carry(const float* __restrict__ hloc,
                                                  const float* __restrict__ Pc,
                                                  float* __restrict__ Hent) {
    int g = blockIdx.x * 256 + threadIdx.x;
    int h = g >> 12;
    int inner = g & 4095;
    int n = g & 15;
    float carry = 0.f;
    for (int c = 0; c < NC; c++) {
        size_t idx = ((size_t)c * NH + h) * (PH * DSTATE) + inner;
        Hent[idx] = carry;
        carry = fmaf(Pc[((size_t)c * NH + h) * DSTATE + n], carry, hloc[idx]);
    }
}

// ---------------- scan phase 3: re-run chunk, gated output in place ----------------
__global__ __launch_bounds__(256) void scan_out(const float* __restrict__ Z,
                                                float* __restrict__ UC,
                                                const float* __restrict__ DBC,
                                                const float* __restrict__ dt,
                                                const float* __restrict__ dA,
                                                const float* __restrict__ Dskip,
                                                const float* __restrict__ Hent) {
    const int c = blockIdx.x, h = blockIdx.y;
    const int pidx = threadIdx.x;
    __shared__ float sdA[LC][DSTATE];
    __shared__ float sdB[LC][DSTATE];
    __shared__ float sC [LC][DSTATE];
    const int st = pidx >> 4, sn = pidx & 15;
    #pragma unroll
    for (int j = 0; j < 4; j++) {
        int t = st + j * 16;
        size_t trow = (size_t)c * LC + t;
        float dtv = dt[trow * NH + h];
        sdA[t][sn] = dA[(trow * NH + h) * DSTATE + sn];
        sdB[t][sn] = dtv * DBC[trow * 320 + 64 + h * DSTATE + sn];
        sC [t][sn] =       DBC[trow * 320 + 192 + h * DSTATE + sn];
    }
    __syncthreads();

    float hst[DSTATE];
    const float* he = Hent + (((size_t)c * NH + h) * PH + pidx) * DSTATE;
    #pragma unroll
    for (int n = 0; n < DSTATE; n++) hst[n] = he[n];
    const float dsk = Dskip[h * PH + pidx];

    for (int t = 0; t < LC; t++) {
        size_t off = ((size_t)c * LC + t) * DINNER + h * PH + pidx;
        float u_p = UC[off];
        float zv  = Z[off];
        float a0 = 0.f, a1 = 0.f, a2 = 0.f, a3 = 0.f;
        #pragma unroll
        for (int n = 0; n < 4; n++) {
            hst[n +  0] = fmaf(hst[n +  0], sdA[t][n +  0], u_p * sdB[t][n +  0]);
            hst[n +  4] = fmaf(hst[n +  4], sdA[t][n +  4], u_p * sdB[t][n +  4]);
            hst[n +  8] = fmaf(hst[n +  8], sdA[t][n +  8], u_p * sdB[t][n +  8]);
            hst[n + 12] = fmaf(hst[n + 12], sdA[t][n + 12], u_p * sdB[t][n + 12]);
            a0 = fmaf(hst[n +  0], sC[t][n +  0], a0);
            a1 = fmaf(hst[n +  4], sC[t][n +  4], a1);
            a2 = fmaf(hst[n +  8], sC[t][n +  8], a2);
            a3 = fmaf(hst[n + 12], sC[t][n + 12], a3);
        }
        float yv = ((a0 + a1) + (a2 + a3)) + dsk * u_p;
        float sil = zv / (1.f + expf(-zv));
        UC[off] = yv * sil;
    }
}

// ---------------- RMSNorm, bf16 output ----------------
__global__ __launch_bounds__(256) void rmsnorm_bf(const float* __restrict__ G,
                                                  const float* __restrict__ norm_w,
                                                  ushort* __restrict__ Gb) {
    const int row = blockIdx.x;
    const float* r = G + (size_t)row * DINNER;
    const int c0 = threadIdx.x * 8;
    float4 v0 = *(const float4*)(r + c0);
    float4 v1 = *(const float4*)(r + c0 + 4);
    float ss = v0.x * v0.x;
    ss = fmaf(v0.y, v0.y, ss); ss = fmaf(v0.z, v0.z, ss); ss = fmaf(v0.w, v0.w, ss);
    ss = fmaf(v1.x, v1.x, ss); ss = fmaf(v1.y, v1.y, ss);
    ss = fmaf(v1.z, v1.z, ss); ss = fmaf(v1.w, v1.w, ss);
    #pragma unroll
    for (int off = 32; off > 0; off >>= 1) ss += __shfl_down(ss, off);
    __shared__ float red[4];
    if ((threadIdx.x & 63) == 0) red[threadIdx.x >> 6] = ss;
    __syncthreads();
    float tot = red[0] + red[1] + red[2] + red[3];
    float inv = rsqrtf(tot / (float)DINNER + 1e-6f);
    float4 w0 = *(const float4*)(norm_w + c0);
    float4 w1 = *(const float4*)(norm_w + c0 + 4);
    uint4 o;
    o.x = cvt2bf(v0.x * inv * w0.x, v0.y * inv * w0.y);
    o.y = cvt2bf(v0.z * inv * w0.z, v0.w * inv * w0.w);
    o.z = cvt2bf(v1.x * inv * w1.x, v1.y * inv * w1.y);
    o.w = cvt2bf(v1.z * inv * w1.z, v1.w * inv * w1.w);
    *(uint4*)(Gb + (size_t)row * DINNER + c0) = o;
}

extern "C" void kernel_launch(void* const* d_in, const int* in_sizes, int n_in,
                              void* d_out, int out_size, void* d_ws, size_t ws_size,
                              hipStream_t stream) {
    const float* x       = (const float*)d_in[0];
    const float* W_in    = (const float*)d_in[1];
    const float* W_dt    = (const float*)d_in[2];
    const float* conv_w  = (const float*)d_in[3];
    const float* conv_b  = (const float*)d_in[4];
    const float* A_log   = (const float*)d_in[5];
    const float* Dskip   = (const float*)d_in[6];
    const float* dt_bias = (const float*)d_in[7];
    const float* norm_w  = (const float*)d_in[8];
    const float* W_out   = (const float*)d_in[9];
    const float* W_res   = (const float*)d_in[10];
    float* out = (float*)d_out;
    float* ws  = (float*)d_ws;

    float* Z    = ws + OFF_Z;
    float* U    = ws + OFF_U;
    float* UC   = ws + OFF_UC;
    float* DBC  = ws + OFF_DBC;
    float* dt   = ws + OFF_DT;
    float* dA   = ws + OFF_DA;
    float* Pc   = ws + OFF_PC;
    float* hloc = U;                                        // U dead after conv
    float* Hent = U + (size_t)2 * 1024 * 1024;
    ushort* Gb  = (ushort*)(U + (size_t)4 * 1024 * 1024);   // bf16 g, 16 MB
    ushort* xbf  = (ushort*)(ws + OFF_XBF);
    ushort* winb = (ushort*)(ws + OFF_WIN);
    ushort* wrsb = (ushort*)(ws + OFF_WRES);
    ushort* wotb = (ushort*)(ws + OFF_WOUT);

    // one-time weight conversions (bf16, W_in zero-padded to 4480 rows)
    cvt_bf<<<(NPAD * DMODEL / 8) / 256, 256, 0, stream>>>(W_in, winb, TOTOUT * DMODEL);
    cvt_bf<<<(DINNER * DMODEL / 8) / 256, 256, 0, stream>>>(W_res, wrsb, DINNER * DMODEL);
    cvt_bf<<<(DMODEL * DINNER / 8) / 256, 256, 0, stream>>>(W_out, wotb, DMODEL * DINNER);

    for (int b = 0; b < 2; b++) {
        const float* xb = x + (size_t)b * M * DMODEL;
        float* outb = out + (size_t)b * M * DMODEL;

        // 0. x -> bf16
        cvt_bf<<<(M * DMODEL / 8) / 256, 256, 0, stream>>>(xb, xbf, M * DMODEL);
        // 1. in-projection (4096 x 4480pad x 1024), split Z | U | DBC
        gemm_bf16<2><<<35 * 32, 256, 0, stream>>>(xbf, winb, Z, U, DBC, 35, DMODEL, 0);
        // 2. causal depthwise conv: U -> UC
        conv_dw<<<(M * DINNER) / 256, 256, 0, stream>>>(U, conv_w, conv_b, UC);
        // 3. dt head + dA table
        dt_kernel<<<(M * NH) / 256, 256, 0, stream>>>(DBC, W_dt, dt_bias, A_log, dt, dA);
        // 4. chunk-parallel scan (+Dskip + silu gating, in-place on UC)
        scan_local<<<dim3(NC, NH), 256, 0, stream>>>(UC, DBC, dt, dA, hloc, Pc);
        scan_carry<<<(NH * PH * DSTATE) / 256, 256, 0, stream>>>(hloc, Pc, Hent);
        scan_out<<<dim3(NC, NH), 256, 0, stream>>>(Z, UC, DBC, dt, dA, Dskip, Hent);
        // 5. residual GEMM accumulate: UC += x @ W_res^T
        gemm_bf16<1><<<16 * 32, 256, 0, stream>>>(xbf, wrsb, UC, nullptr, nullptr, 16, DMODEL, DINNER);
        // 6. RMSNorm -> bf16 g
        rmsnorm_bf<<<M, 256, 0, stream>>>(UC, norm_w, Gb);
        // 7. out-projection: out = g @ W_out^T
        gemm_bf16<0><<<8 * 32, 256, 0, stream>>>(Gb, wotb, outb, nullptr, nullptr, 8, DINNER, DMODEL);
    }
}

// Round 6
// 369.886 us; speedup vs baseline: 13.6556x; 1.5358x over previous
//
#include <hip/hip_runtime.h>
#include <hip/hip_bf16.h>
#include <math.h>

#define DMODEL  1024
#define DINNER  2048
#define DSTATE  16
#define DCONV   4
#define DTRANK  64
#define NH      8
#define PH      256
#define TOTOUT  4416
#define NPAD    4480            // TOTOUT padded to 128 multiple
#define MB_ROWS 4096            // rows per batch
#define LC      64              // scan chunk length
#define NCB     (MB_ROWS/LC)    // 64 chunks per batch

typedef __attribute__((ext_vector_type(8))) short bf16x8;
typedef __attribute__((ext_vector_type(4))) float f32x4;

__device__ inline unsigned cvt2bf(float lo, float hi) {
    unsigned r;
    asm("v_cvt_pk_bf16_f32 %0, %1, %2" : "=v"(r) : "v"(lo), "v"(hi));
    return r;
}
__device__ inline ushort f2bf(float v) { return (ushort)(cvt2bf(v, v) & 0xffffu); }
__device__ inline float bf2f(ushort u) {
    union { unsigned u; float f; } w; w.u = (unsigned)u << 16; return w.f;
}
__device__ inline void gload16(const ushort* g, ushort* l) {
    __builtin_amdgcn_global_load_lds((const __attribute__((address_space(1))) unsigned*)(const void*)g,
                                     (__attribute__((address_space(3))) unsigned*)(void*)l, 16, 0, 0);
}

// ---------------- fp32 -> bf16 convert ----------------
__global__ __launch_bounds__(256) void cvt_bf(const float* __restrict__ s,
                                              ushort* __restrict__ d) {
    size_t i = ((size_t)blockIdx.x * 256 + threadIdx.x) * 8;
    float4 v0 = *(const float4*)(s + i);
    float4 v1 = *(const float4*)(s + i + 4);
    uint4 o;
    o.x = cvt2bf(v0.x, v0.y); o.y = cvt2bf(v0.z, v0.w);
    o.z = cvt2bf(v1.x, v1.y); o.w = cvt2bf(v1.z, v1.w);
    *(uint4*)(d + i) = o;
}

// ---------------- fused weight convert: [W_in pad4480 | W_res | W_out] ----------------
__global__ __launch_bounds__(256) void cvt_weights(const float* __restrict__ W_in,
                                                   const float* __restrict__ W_res,
                                                   const float* __restrict__ W_out,
                                                   ushort* __restrict__ dst) {
    const size_t R0v = (size_t)TOTOUT * DMODEL;
    const size_t R0  = (size_t)NPAD * DMODEL;
    const size_t R1  = R0 + (size_t)DINNER * DMODEL;
    size_t i = ((size_t)blockIdx.x * 256 + threadIdx.x) * 8;
    float4 v0, v1;
    if (i < R0) {
        if (i < R0v) { v0 = *(const float4*)(W_in + i); v1 = *(const float4*)(W_in + i + 4); }
        else { v0 = make_float4(0.f,0.f,0.f,0.f); v1 = v0; }
    } else if (i < R1) {
        size_t o = i - R0; v0 = *(const float4*)(W_res + o); v1 = *(const float4*)(W_res + o + 4);
    } else {
        size_t o = i - R1; v0 = *(const float4*)(W_out + o); v1 = *(const float4*)(W_out + o + 4);
    }
    uint4 o;
    o.x = cvt2bf(v0.x, v0.y); o.y = cvt2bf(v0.z, v0.w);
    o.z = cvt2bf(v1.x, v1.y); o.w = cvt2bf(v1.z, v1.w);
    *(uint4*)(dst + i) = o;
}

// ================= bf16 MFMA GEMM, 2-phase double-buffered =================
// C (op)= A[Mr x K]bf16 x W[N x K]bf16^T; 128x128 tile, BK=32, 4 waves,
// global_load_lds width-16; prefetch next K-tile into other buffer each iter.
// MODE 0: C0 = acc (fp32, ldc) ; MODE 1: C0 += acc ; MODE 2: split Zb|Ub|DBC.
template<int MODE>
__global__ __launch_bounds__(256) void gemm_bf16(const ushort* __restrict__ A,
                                                 const ushort* __restrict__ W,
                                                 float* __restrict__ C0,
                                                 ushort* __restrict__ Zb,
                                                 ushort* __restrict__ Ub,
                                                 float* __restrict__ DBCp,
                                                 int ntx, int K, int ldc) {
    __shared__ __align__(16) ushort Al[2][128 * 32];
    __shared__ __align__(16) ushort Bl[2][128 * 32];
    const int nwg  = gridDim.x;
    const int orig = blockIdx.x;
    const int swz  = (orig & 7) * (nwg >> 3) + (orig >> 3);   // bijective: nwg % 8 == 0
    const int bx = swz % ntx, by = swz / ntx;
    const int row0 = by * 128, col0 = bx * 128;

    const int t    = threadIdx.x;
    const int lane = t & 63, w = t >> 6;
    const int wr   = w >> 1, wc = w & 1;
    const int l15  = lane & 15, l4 = lane >> 4;

    // staging granule: t covers LDS ushorts [t*8, t*8+8) = row t>>2, k (t&3)*8
    const int gr = t >> 2, gk = (t & 3) * 8;
    const ushort* Ag  = A + (size_t)(row0 + gr) * K + gk;
    const ushort* Ag2 = Ag + (size_t)64 * K;
    const ushort* Wg  = W + (size_t)(col0 + gr) * K + gk;
    const ushort* Wg2 = Wg + (size_t)64 * K;

    f32x4 acc[4][4];
    #pragma unroll
    for (int i = 0; i < 4; i++)
        #pragma unroll
        for (int j = 0; j < 4; j++)
            acc[i][j] = (f32x4){0.f, 0.f, 0.f, 0.f};

    // prologue: stage K-tile 0 into buffer 0
    gload16(Ag,  &Al[0][t * 8]);
    gload16(Ag2, &Al[0][2048 + t * 8]);
    gload16(Wg,  &Bl[0][t * 8]);
    gload16(Wg2, &Bl[0][2048 + t * 8]);
    __syncthreads();

    const int KT = K >> 5;
    for (int kt = 0; kt < KT; ++kt) {
        const int cur = kt & 1;
        if (kt + 1 < KT) {   // prefetch next tile into other buffer (overlaps MFMA)
            const int ko = (kt + 1) << 5;
            gload16(Ag + ko,  &Al[cur ^ 1][t * 8]);
            gload16(Ag2 + ko, &Al[cur ^ 1][2048 + t * 8]);
            gload16(Wg + ko,  &Bl[cur ^ 1][t * 8]);
            gload16(Wg2 + ko, &Bl[cur ^ 1][2048 + t * 8]);
        }
        const bf16x8* Av = (const bf16x8*)Al[cur];
        const bf16x8* Bv = (const bf16x8*)Bl[cur];
        bf16x8 af[4], bw[4];
        #pragma unroll
        for (int mi = 0; mi < 4; mi++)
            af[mi] = Av[(wr * 64 + mi * 16 + l15) * 4 + l4];
        #pragma unroll
        for (int ni = 0; ni < 4; ni++)
            bw[ni] = Bv[(wc * 64 + ni * 16 + l15) * 4 + l4];
        #pragma unroll
        for (int mi = 0; mi < 4; mi++)
            #pragma unroll
            for (int ni = 0; ni < 4; ni++)
                acc[mi][ni] = __builtin_amdgcn_mfma_f32_16x16x32_bf16(af[mi], bw[ni], acc[mi][ni], 0, 0, 0);
        __syncthreads();   // drains vmcnt (next tile landed) + all reads of cur done
    }

    // epilogue: C/D layout col=lane&15, row=(lane>>4)*4+reg  [m89/m91]
    #pragma unroll
    for (int mi = 0; mi < 4; mi++) {
        #pragma unroll
        for (int ni = 0; ni < 4; ni++) {
            #pragma unroll
            for (int r = 0; r < 4; r++) {
                const int row = row0 + wr * 64 + mi * 16 + l4 * 4 + r;
                const int col = col0 + wc * 64 + ni * 16 + l15;
                const float v = acc[mi][ni][r];
                if (MODE == 0) {
                    C0[(size_t)row * ldc + col] = v;
                } else if (MODE == 1) {
                    C0[(size_t)row * ldc + col] += v;
                } else {
                    if (col0 < DINNER) {
                        Zb[(size_t)row * DINNER + col] = f2bf(v);
                    } else if (col0 < 2 * DINNER) {
                        Ub[(size_t)row * DINNER + (col - DINNER)] = f2bf(v);
                    } else if (col < TOTOUT) {
                        DBCp[(size_t)row * 320 + (col - 2 * DINNER)] = v;
                    }
                }
            }
        }
    }
}

// ---------------- dt head + dA table ----------------
__global__ __launch_bounds__(256) void dt_kernel(const float* __restrict__ DBC,
                                                 const float* __restrict__ W_dt,
                                                 const float* __restrict__ dt_bias,
                                                 const float* __restrict__ A_log,
                                                 float* __restrict__ dt,
                                                 float* __restrict__ dA) {
    int idx = blockIdx.x * blockDim.x + threadIdx.x;   // t*NH + h
    int h = idx % NH;
    int tr = idx / NH;
    const float* row = DBC + (size_t)tr * 320;
    float acc = dt_bias[h];
    #pragma unroll
    for (int r = 0; r < DTRANK; r++) acc = fmaf(row[r], W_dt[h * DTRANK + r], acc);
    float sp = acc > 20.f ? acc : log1pf(expf(acc));
    sp = fminf(fmaxf(sp, 1e-4f), 1.0f);
    dt[idx] = sp;
    #pragma unroll
    for (int n = 0; n < DSTATE; n++)
        dA[(size_t)idx * DSTATE + n] = expf(sp * (-expf(A_log[h * DSTATE + n])));
}

// ---------------- scan phase 1: fused conv + per-chunk local end-state ----------------
__global__ __launch_bounds__(256) void scan_local(const ushort* __restrict__ Ub,
                                                  const float* __restrict__ DBC,
                                                  const float* __restrict__ dt_,
                                                  const float* __restrict__ dA_,
                                                  const float* __restrict__ cw,
                                                  const float* __restrict__ cb,
                                                  float* __restrict__ hloc,
                                                  float* __restrict__ Pc) {
    const int c = blockIdx.x, h = blockIdx.y;
    const int pidx = threadIdx.x;
    const int ch = h * PH + pidx;
    const int t0 = c * LC;
    __shared__ float sdA[LC][DSTATE];
    __shared__ float sdB[LC][DSTATE];   // dt * B
    const int st = pidx >> 4, sn = pidx & 15;
    #pragma unroll
    for (int j = 0; j < 4; j++) {
        int tt = st + j * 16;
        size_t trow = (size_t)(t0 + tt);
        float dv = dt_[trow * NH + h];
        sdA[tt][sn] = dA_[(trow * NH + h) * DSTATE + sn];
        sdB[tt][sn] = dv * DBC[trow * 320 + 64 + h * DSTATE + sn];
    }
    // conv state (zero-pad at batch start)
    const float w0 = cw[ch * 4], w1 = cw[ch * 4 + 1], w2 = cw[ch * 4 + 2], w3 = cw[ch * 4 + 3];
    const float bia = cb[ch];
    const int bs = (c / NCB) * MB_ROWS;
    float um3 = (t0 - 3 >= bs) ? bf2f(Ub[(size_t)(t0 - 3) * DINNER + ch]) : 0.f;
    float um2 = (t0 - 2 >= bs) ? bf2f(Ub[(size_t)(t0 - 2) * DINNER + ch]) : 0.f;
    float um1 = (t0 - 1 >= bs) ? bf2f(Ub[(size_t)(t0 - 1) * DINNER + ch]) : 0.f;
    __syncthreads();

    float hst[DSTATE] = {};
    for (int t = 0; t < LC; t++) {
        float u0 = bf2f(Ub[(size_t)(t0 + t) * DINNER + ch]);
        float up = fmaf(w3, u0, fmaf(w2, um1, fmaf(w1, um2, fmaf(w0, um3, bia))));
        um3 = um2; um2 = um1; um1 = u0;
        #pragma unroll
        for (int n = 0; n < DSTATE; n++)
            hst[n] = fmaf(hst[n], sdA[t][n], up * sdB[t][n]);
    }
    float* hl = hloc + (((size_t)c * NH + h) * PH + pidx) * DSTATE;
    #pragma unroll
    for (int n = 0; n < DSTATE; n++) hl[n] = hst[n];

    if (pidx < DSTATE) {
        float pr = 1.f;
        for (int t = 0; t < LC; t++) pr *= sdA[t][pidx];
        Pc[((size_t)c * NH + h) * DSTATE + pidx] = pr;
    }
}

// ---------------- scan phase 2: serial carry across chunks (per batch) ----------------
__global__ __launch_bounds__(256) void scan_carry(const float* __restrict__ hloc,
                                                  const float* __restrict__ Pc,
                                                  float* __restrict__ Hent) {
    int g = blockIdx.x * 256 + threadIdx.x;    // nb*32768 threads
    int b = g >> 15;
    int r = g & 32767;
    int h = r >> 12;
    int inner = r & 4095;
    int n = r & 15;
    float carry = 0.f;
    for (int i = 0; i < NCB; i++) {
        int c = b * NCB + i;
        size_t idx = ((size_t)c * NH + h) * (PH * DSTATE) + inner;
        Hent[idx] = carry;
        carry = fmaf(Pc[((size_t)c * NH + h) * DSTATE + n], carry, hloc[idx]);
    }
}

// ---------------- scan phase 3: fused conv + re-run chunk + skip + silu gate ----------------
__global__ __launch_bounds__(256) void scan_out(const ushort* __restrict__ Zb,
                                                const ushort* __restrict__ Ub,
                                                float* __restrict__ UC,
                                                const float* __restrict__ DBC,
                                                const float* __restrict__ dt_,
                                                const float* __restrict__ dA_,
                                                const float* __restrict__ cw,
                                                const float* __restrict__ cb,
                                                const float* __restrict__ Dskip,
                                                const float* __restrict__ Hent) {
    const int c = blockIdx.x, h = blockIdx.y;
    const int pidx = threadIdx.x;
    const int ch = h * PH + pidx;
    const int t0 = c * LC;
    __shared__ float sdA[LC][DSTATE];
    __shared__ float sdB[LC][DSTATE];
    __shared__ float sC [LC][DSTATE];
    const int st = pidx >> 4, sn = pidx & 15;
    #pragma unroll
    for (int j = 0; j < 4; j++) {
        int tt = st + j * 16;
        size_t trow = (size_t)(t0 + tt);
        float dv = dt_[trow * NH + h];
        sdA[tt][sn] = dA_[(trow * NH + h) * DSTATE + sn];
        sdB[tt][sn] = dv * DBC[trow * 320 + 64 + h * DSTATE + sn];
        sC [tt][sn] =      DBC[trow * 320 + 192 + h * DSTATE + sn];
    }
    const float w0 = cw[ch * 4], w1 = cw[ch * 4 + 1], w2 = cw[ch * 4 + 2], w3 = cw[ch * 4 + 3];
    const float bia = cb[ch];
    const int bs = (c / NCB) * MB_ROWS;
    float um3 = (t0 - 3 >= bs) ? bf2f(Ub[(size_t)(t0 - 3) * DINNER + ch]) : 0.f;
    float um2 = (t0 - 2 >= bs) ? bf2f(Ub[(size_t)(t0 - 2) * DINNER + ch]) : 0.f;
    float um1 = (t0 - 1 >= bs) ? bf2f(Ub[(size_t)(t0 - 1) * DINNER + ch]) : 0.f;
    const float dsk = Dskip[ch];
    float hst[DSTATE];
    const float* he = Hent + (((size_t)c * NH + h) * PH + pidx) * DSTATE;
    #pragma unroll
    for (int n = 0; n < DSTATE; n++) hst[n] = he[n];
    __syncthreads();

    for (int t = 0; t < LC; t++) {
        size_t off = (size_t)(t0 + t) * DINNER + ch;
        float u0 = bf2f(Ub[off]);
        float up = fmaf(w3, u0, fmaf(w2, um1, fmaf(w1, um2, fmaf(w0, um3, bia))));
        um3 = um2; um2 = um1; um1 = u0;
        float a0 = 0.f, a1 = 0.f, a2 = 0.f, a3 = 0.f;
        #pragma unroll
        for (int n = 0; n < 4; n++) {
            hst[n +  0] = fmaf(hst[n +  0], sdA[t][n +  0], up * sdB[t][n +  0]);
            hst[n +  4] = fmaf(hst[n +  4], sdA[t][n +  4], up * sdB[t][n +  4]);
            hst[n +  8] = fmaf(hst[n +  8], sdA[t][n +  8], up * sdB[t][n +  8]);
            hst[n + 12] = fmaf(hst[n + 12], sdA[t][n + 12], up * sdB[t][n + 12]);
            a0 = fmaf(hst[n +  0], sC[t][n +  0], a0);
            a1 = fmaf(hst[n +  4], sC[t][n +  4], a1);
            a2 = fmaf(hst[n +  8], sC[t][n +  8], a2);
            a3 = fmaf(hst[n + 12], sC[t][n + 12], a3);
        }
        float yv = ((a0 + a1) + (a2 + a3)) + dsk * up;
        float zv = bf2f(Zb[off]);
        float sil = zv / (1.f + expf(-zv));
        UC[off] = yv * sil;
    }
}

// ---------------- RMSNorm, bf16 output ----------------
__global__ __launch_bounds__(256) void rmsnorm_bf(const float* __restrict__ G,
                                                  const float* __restrict__ norm_w,
                                                  ushort* __restrict__ Gb) {
    const int row = blockIdx.x;
    const float* r = G + (size_t)row * DINNER;
    const int c0 = threadIdx.x * 8;
    float4 v0 = *(const float4*)(r + c0);
    float4 v1 = *(const float4*)(r + c0 + 4);
    float ss = v0.x * v0.x;
    ss = fmaf(v0.y, v0.y, ss); ss = fmaf(v0.z, v0.z, ss); ss = fmaf(v0.w, v0.w, ss);
    ss = fmaf(v1.x, v1.x, ss); ss = fmaf(v1.y, v1.y, ss);
    ss = fmaf(v1.z, v1.z, ss); ss = fmaf(v1.w, v1.w, ss);
    #pragma unroll
    for (int off = 32; off > 0; off >>= 1) ss += __shfl_down(ss, off);
    __shared__ float red[4];
    if ((threadIdx.x & 63) == 0) red[threadIdx.x >> 6] = ss;
    __syncthreads();
    float tot = red[0] + red[1] + red[2] + red[3];
    float inv = rsqrtf(tot / (float)DINNER + 1e-6f);
    float4 w0 = *(const float4*)(norm_w + c0);
    float4 w1 = *(const float4*)(norm_w + c0 + 4);
    uint4 o;
    o.x = cvt2bf(v0.x * inv * w0.x, v0.y * inv * w0.y);
    o.y = cvt2bf(v0.z * inv * w0.z, v0.w * inv * w0.w);
    o.z = cvt2bf(v1.x * inv * w1.x, v1.y * inv * w1.y);
    o.w = cvt2bf(v1.z * inv * w1.z, v1.w * inv * w1.w);
    *(uint4*)(Gb + (size_t)row * DINNER + c0) = o;
}

// ---------------- workspace layout ----------------
struct Lay {
    float *UC, *DBC, *DT, *DA, *PC, *HLOC, *HENT;
    ushort *ZB, *UB, *XBF, *WB;
    size_t total;
};
static Lay mk_layout(char* base, int Mr) {
    size_t o = 0;
    auto take = [&](size_t bytes) { char* p = base + o; o = (o + bytes + 255) & ~(size_t)255; return p; };
    Lay l;
    l.UC   = (float*) take((size_t)Mr * 2048 * 4);
    l.DBC  = (float*) take((size_t)Mr * 320 * 4);
    l.DT   = (float*) take((size_t)Mr * 8 * 4);
    l.DA   = (float*) take((size_t)Mr * 128 * 4);
    l.PC   = (float*) take((size_t)(Mr / 64) * NH * DSTATE * 4);
    l.HLOC = (float*) take((size_t)Mr * 512 * 4);
    l.HENT = (float*) take((size_t)Mr * 512 * 4);
    l.ZB   = (ushort*)take((size_t)Mr * 2048 * 2);
    l.UB   = (ushort*)take((size_t)Mr * 2048 * 2);
    l.XBF  = (ushort*)take((size_t)8192 * 1024 * 2);
    l.WB   = (ushort*)take(((size_t)NPAD * 1024 + (size_t)2048 * 1024 + (size_t)1024 * 2048) * 2);
    l.total = o;
    return l;
}

extern "C" void kernel_launch(void* const* d_in, const int* in_sizes, int n_in,
                              void* d_out, int out_size, void* d_ws, size_t ws_size,
                              hipStream_t stream) {
    const float* x       = (const float*)d_in[0];
    const float* W_in    = (const float*)d_in[1];
    const float* W_dt    = (const float*)d_in[2];
    const float* conv_w  = (const float*)d_in[3];
    const float* conv_b  = (const float*)d_in[4];
    const float* A_log   = (const float*)d_in[5];
    const float* Dskip   = (const float*)d_in[6];
    const float* dt_bias = (const float*)d_in[7];
    const float* norm_w  = (const float*)d_in[8];
    const float* W_out   = (const float*)d_in[9];
    const float* W_res   = (const float*)d_in[10];
    float* out = (float*)d_out;

    // choose single-pass (both batches, M=8192) if workspace allows, else per-batch
    Lay probe = mk_layout(nullptr, 2 * MB_ROWS);
    const bool fat = ws_size >= probe.total;
    const int Mr = fat ? 2 * MB_ROWS : MB_ROWS;
    const int npass = fat ? 1 : 2;
    const int nbc = fat ? 2 : 1;          // batches handled per call (for carry/conv reset)
    Lay l = mk_layout((char*)d_ws, Mr);

    ushort* winb = l.WB;
    ushort* wrsb = winb + (size_t)NPAD * 1024;
    ushort* wotb = wrsb + (size_t)2048 * 1024;
    ushort* Gb   = l.ZB;                  // Z dead after scan_out; reuse for g (same size)

    // one-time conversions
    cvt_weights<<<4288, 256, 0, stream>>>(W_in, W_res, W_out, l.WB);
    cvt_bf<<<(2 * MB_ROWS * DMODEL / 8) / 256, 256, 0, stream>>>(x, l.XBF);

    const int NT = Mr / 128;              // M-tiles per pass
    for (int b = 0; b < npass; b++) {
        const ushort* xb = l.XBF + (size_t)b * MB_ROWS * DMODEL;
        float* outb = out + (size_t)b * MB_ROWS * DMODEL;

        // 1. in-projection (Mr x 4480pad x 1024) -> Zb(bf16) | Ub(bf16) | DBC(fp32)
        gemm_bf16<2><<<35 * NT, 256, 0, stream>>>(xb, winb, nullptr, l.ZB, l.UB, l.DBC, 35, DMODEL, 0);
        // 2. dt head + dA table
        dt_kernel<<<(Mr * NH) / 256, 256, 0, stream>>>(l.DBC, W_dt, dt_bias, A_log, l.DT, l.DA);
        // 3. chunk-parallel scan with fused causal conv; gated y -> UC (fp32)
        scan_local<<<dim3(Mr / LC, NH), 256, 0, stream>>>(l.UB, l.DBC, l.DT, l.DA, conv_w, conv_b, l.HLOC, l.PC);
        scan_carry<<<nbc * 128, 256, 0, stream>>>(l.HLOC, l.PC, l.HENT);
        scan_out<<<dim3(Mr / LC, NH), 256, 0, stream>>>(l.ZB, l.UB, l.UC, l.DBC, l.DT, l.DA,
                                                        conv_w, conv_b, Dskip, l.HENT);
        // 4. residual GEMM accumulate: UC += x @ W_res^T
        gemm_bf16<1><<<16 * NT, 256, 0, stream>>>(xb, wrsb, l.UC, nullptr, nullptr, nullptr, 16, DMODEL, DINNER);
        // 5. RMSNorm -> bf16 g (over Zb storage)
        rmsnorm_bf<<<Mr, 256, 0, stream>>>(l.UC, norm_w, Gb);
        // 6. out-projection: out = g @ W_out^T
        gemm_bf16<0><<<8 * NT, 256, 0, stream>>>(Gb, wotb, outb, nullptr, nullptr, nullptr, 8, DINNER, DMODEL);
    }
}

// Round 7
// 307.543 us; speedup vs baseline: 16.4238x; 1.2027x over previous
//
#include <hip/hip_runtime.h>
#include <hip/hip_bf16.h>
#include <math.h>

#define DMODEL  1024
#define DINNER  2048
#define DSTATE  16
#define DCONV   4
#define DTRANK  64
#define NH      8
#define PH      256
#define TOTOUT  4416
#define NPAD    4480            // TOTOUT padded to 128 multiple
#define MB_ROWS 4096            // rows per batch
#define LC      64              // scan chunk length
#define NCB     (MB_ROWS/LC)    // 64 chunks per batch

typedef __attribute__((ext_vector_type(8))) short bf16x8;
typedef __attribute__((ext_vector_type(4))) float f32x4;

__device__ inline unsigned cvt2bf(float lo, float hi) {
    unsigned r;
    asm("v_cvt_pk_bf16_f32 %0, %1, %2" : "=v"(r) : "v"(lo), "v"(hi));
    return r;
}
__device__ inline ushort f2bf(float v) { return (ushort)(cvt2bf(v, v) & 0xffffu); }
__device__ inline float bf2f(ushort u) {
    union { unsigned u; float f; } w; w.u = (unsigned)u << 16; return w.f;
}
__device__ inline void gload16(const ushort* g, ushort* l) {
    __builtin_amdgcn_global_load_lds((const __attribute__((address_space(1))) unsigned*)(const void*)g,
                                     (__attribute__((address_space(3))) unsigned*)(void*)l, 16, 0, 0);
}

// ---------------- fp32 -> bf16 convert ----------------
__global__ __launch_bounds__(256) void cvt_bf(const float* __restrict__ s,
                                              ushort* __restrict__ d) {
    size_t i = ((size_t)blockIdx.x * 256 + threadIdx.x) * 8;
    float4 v0 = *(const float4*)(s + i);
    float4 v1 = *(const float4*)(s + i + 4);
    uint4 o;
    o.x = cvt2bf(v0.x, v0.y); o.y = cvt2bf(v0.z, v0.w);
    o.z = cvt2bf(v1.x, v1.y); o.w = cvt2bf(v1.z, v1.w);
    *(uint4*)(d + i) = o;
}

// ---------------- fused weight convert: [W_in pad4480 | W_res | W_out] ----------------
__global__ __launch_bounds__(256) void cvt_weights(const float* __restrict__ W_in,
                                                   const float* __restrict__ W_res,
                                                   const float* __restrict__ W_out,
                                                   ushort* __restrict__ dst) {
    const size_t R0v = (size_t)TOTOUT * DMODEL;
    const size_t R0  = (size_t)NPAD * DMODEL;
    const size_t R1  = R0 + (size_t)DINNER * DMODEL;
    size_t i = ((size_t)blockIdx.x * 256 + threadIdx.x) * 8;
    float4 v0, v1;
    if (i < R0) {
        if (i < R0v) { v0 = *(const float4*)(W_in + i); v1 = *(const float4*)(W_in + i + 4); }
        else { v0 = make_float4(0.f,0.f,0.f,0.f); v1 = v0; }
    } else if (i < R1) {
        size_t o = i - R0; v0 = *(const float4*)(W_res + o); v1 = *(const float4*)(W_res + o + 4);
    } else {
        size_t o = i - R1; v0 = *(const float4*)(W_out + o); v1 = *(const float4*)(W_out + o + 4);
    }
    uint4 o;
    o.x = cvt2bf(v0.x, v0.y); o.y = cvt2bf(v0.z, v0.w);
    o.z = cvt2bf(v1.x, v1.y); o.w = cvt2bf(v1.z, v1.w);
    *(uint4*)(dst + i) = o;
}

// ================= bf16 MFMA GEMM: tri-buffer, counted-vmcnt pipeline =================
// C (op)= A[Mr x K]bf16 x W[N x K]bf16^T; 256x128 tile, BK=32, 8 waves (4M x 2N),
// 3 LDS buffers, depth-2 global_load_lds prefetch, one raw s_barrier per K-step,
// vmcnt(3) counted (never 0 in steady state). LDS XOR-swizzle (both-sides, rule #21):
// linear dest + inverse-permuted global source + swizzled read.
// MODE 0: C0 = acc (fp32, ldc) ; MODE 1: Cb(bf16) += acc ; MODE 2: split Zb|Ub|DBC.
template<int MODE>
__global__ __launch_bounds__(512) void gemm_p(const ushort* __restrict__ A,
                                              const ushort* __restrict__ W,
                                              float* __restrict__ C0,
                                              ushort* __restrict__ Cb,
                                              ushort* __restrict__ Zb,
                                              ushort* __restrict__ Ub,
                                              float* __restrict__ DBCp,
                                              int ntx, int K, int ldc) {
    // per buffer: A 256x32 (8192 ushorts) + B 128x32 (4096 ushorts) = 12288 ushorts (24 KB)
    __shared__ __align__(16) ushort L[3 * 12288];
    const int nwg  = gridDim.x;
    const int orig = blockIdx.x;
    const int swz  = (orig & 7) * (nwg >> 3) + (orig >> 3);   // bijective: nwg % 8 == 0
    const int bx = swz % ntx, by = swz / ntx;
    const int row0 = by * 256, col0 = bx * 128;

    const int t    = threadIdx.x;
    const int lane = t & 63, w = t >> 6;
    const int wr   = w >> 1, wc = w & 1;       // 4 M-waves x 2 N-waves
    const int l15  = lane & 15, l4 = lane >> 4;

    // ---- staging sources (swizzled): linear LDS granule (r,s) holds global
    // (row r^((r>>3)&1), chunk s^((r>>1)&3)); read XOR-mask ((r>>1)&7)<<3 inverts it.
    const int r0g = t >> 2, s0g = t & 3;                 // A granule t (rows 0-127), B granule t
    const int r1g = r0g + 128;                           // A granule t+512 (rows 128-255)
    const int rr0 = r0g ^ ((r0g >> 3) & 1), cc0 = s0g ^ ((r0g >> 1) & 3);
    const int rr1 = r1g ^ ((r1g >> 3) & 1), cc1 = s0g ^ ((r1g >> 1) & 3);
    const ushort* sA0 = A + (size_t)(row0 + rr0) * K + cc0 * 8;
    const ushort* sA1 = A + (size_t)(row0 + rr1) * K + cc1 * 8;
    const ushort* sB0 = W + (size_t)(col0 + rr0) * K + cc0 * 8;

    // ---- fragment LDS offsets (ushort units), precomputed with read-side swizzle
    int offA[4], offB[4];
    #pragma unroll
    for (int mi = 0; mi < 4; mi++) {
        int r = wr * 64 + mi * 16 + l15;
        offA[mi] = (r * 32 + l4 * 8) ^ (((r >> 1) & 7) << 3);
    }
    #pragma unroll
    for (int ni = 0; ni < 4; ni++) {
        int r = wc * 64 + ni * 16 + l15;
        offB[ni] = 8192 + ((r * 32 + l4 * 8) ^ (((r >> 1) & 7) << 3));
    }

    f32x4 acc[4][4];
    #pragma unroll
    for (int i = 0; i < 4; i++)
        #pragma unroll
        for (int j = 0; j < 4; j++)
            acc[i][j] = (f32x4){0.f, 0.f, 0.f, 0.f};

    const int KT = K >> 5;
    // prologue: stage T0 -> buf0, T1 -> buf1
    {
        gload16(sA0,      &L[t * 8]);
        gload16(sA1,      &L[4096 + t * 8]);
        gload16(sB0,      &L[8192 + t * 8]);
        gload16(sA0 + 32, &L[12288 + t * 8]);
        gload16(sA1 + 32, &L[12288 + 4096 + t * 8]);
        gload16(sB0 + 32, &L[12288 + 8192 + t * 8]);
    }
    asm volatile("s_waitcnt vmcnt(3)" ::: "memory");   // T0 landed; T1 in flight
    __builtin_amdgcn_sched_barrier(0);
    __builtin_amdgcn_s_barrier();
    __builtin_amdgcn_sched_barrier(0);

    for (int kt = 0; kt < KT; ++kt) {
        const bool pre = (kt + 2) < KT;
        if (pre) {   // stage T_{kt+2} into buffer freed at previous barrier
            ushort* bp2 = &L[((kt + 2) % 3) * 12288];
            const int ko = (kt + 2) << 5;
            gload16(sA0 + ko, bp2 + t * 8);
            gload16(sA1 + ko, bp2 + 4096 + t * 8);
            gload16(sB0 + ko, bp2 + 8192 + t * 8);
        }
        const ushort* bp = &L[(kt % 3) * 12288];
        bf16x8 af[4], bw[4];
        #pragma unroll
        for (int mi = 0; mi < 4; mi++) af[mi] = *(const bf16x8*)(bp + offA[mi]);
        #pragma unroll
        for (int ni = 0; ni < 4; ni++) bw[ni] = *(const bf16x8*)(bp + offB[ni]);
        __builtin_amdgcn_s_setprio(1);
        #pragma unroll
        for (int mi = 0; mi < 4; mi++)
            #pragma unroll
            for (int ni = 0; ni < 4; ni++)
                acc[mi][ni] = __builtin_amdgcn_mfma_f32_16x16x32_bf16(af[mi], bw[ni], acc[mi][ni], 0, 0, 0);
        __builtin_amdgcn_s_setprio(0);
        if (pre) { asm volatile("s_waitcnt vmcnt(3)" ::: "memory"); }   // T_{kt+1} landed
        else     { asm volatile("s_waitcnt vmcnt(0)" ::: "memory"); }
        __builtin_amdgcn_sched_barrier(0);
        __builtin_amdgcn_s_barrier();
        __builtin_amdgcn_sched_barrier(0);
    }

    // epilogue: C/D layout col=lane&15, row=(lane>>4)*4+reg  [m89/m91]
    #pragma unroll
    for (int mi = 0; mi < 4; mi++) {
        #pragma unroll
        for (int ni = 0; ni < 4; ni++) {
            #pragma unroll
            for (int r = 0; r < 4; r++) {
                const int row = row0 + wr * 64 + mi * 16 + l4 * 4 + r;
                const int col = col0 + wc * 64 + ni * 16 + l15;
                const float v = acc[mi][ni][r];
                if (MODE == 0) {
                    C0[(size_t)row * ldc + col] = v;
                } else if (MODE == 1) {
                    size_t idx = (size_t)row * ldc + col;
                    Cb[idx] = f2bf(bf2f(Cb[idx]) + v);
                } else {
                    if (col0 < DINNER) {
                        Zb[(size_t)row * DINNER + col] = f2bf(v);
                    } else if (col0 < 2 * DINNER) {
                        Ub[(size_t)row * DINNER + (col - DINNER)] = f2bf(v);
                    } else if (col < TOTOUT) {
                        DBCp[(size_t)row * 320 + (col - 2 * DINNER)] = v;
                    }
                }
            }
        }
    }
}

// ---------------- dt head + dA table ----------------
__global__ __launch_bounds__(256) void dt_kernel(const float* __restrict__ DBC,
                                                 const float* __restrict__ W_dt,
                                                 const float* __restrict__ dt_bias,
                                                 const float* __restrict__ A_log,
                                                 float* __restrict__ dt,
                                                 float* __restrict__ dA) {
    int idx = blockIdx.x * blockDim.x + threadIdx.x;   // t*NH + h
    int h = idx % NH;
    int tr = idx / NH;
    const float* row = DBC + (size_t)tr * 320;
    float acc = dt_bias[h];
    #pragma unroll
    for (int r = 0; r < DTRANK; r++) acc = fmaf(row[r], W_dt[h * DTRANK + r], acc);
    float sp = acc > 20.f ? acc : log1pf(expf(acc));
    sp = fminf(fmaxf(sp, 1e-4f), 1.0f);
    dt[idx] = sp;
    #pragma unroll
    for (int n = 0; n < DSTATE; n++)
        dA[(size_t)idx * DSTATE + n] = expf(sp * (-expf(A_log[h * DSTATE + n])));
}

// ---------------- scan phase 1: fused conv + per-chunk local end-state ----------------
__global__ __launch_bounds__(256) void scan_local(const ushort* __restrict__ Ub,
                                                  const float* __restrict__ DBC,
                                                  const float* __restrict__ dt_,
                                                  const float* __restrict__ dA_,
                                                  const float* __restrict__ cw,
                                                  const float* __restrict__ cb,
                                                  float* __restrict__ hloc,
                                                  float* __restrict__ Pc) {
    const int c = blockIdx.x, h = blockIdx.y;
    const int pidx = threadIdx.x;
    const int ch = h * PH + pidx;
    const int t0 = c * LC;
    __shared__ float sdA[LC][DSTATE];
    __shared__ float sdB[LC][DSTATE];   // dt * B
    const int st = pidx >> 4, sn = pidx & 15;
    #pragma unroll
    for (int j = 0; j < 4; j++) {
        int tt = st + j * 16;
        size_t trow = (size_t)(t0 + tt);
        float dv = dt_[trow * NH + h];
        sdA[tt][sn] = dA_[(trow * NH + h) * DSTATE + sn];
        sdB[tt][sn] = dv * DBC[trow * 320 + 64 + h * DSTATE + sn];
    }
    const float w0 = cw[ch * 4], w1 = cw[ch * 4 + 1], w2 = cw[ch * 4 + 2], w3 = cw[ch * 4 + 3];
    const float bia = cb[ch];
    const int bs = (c / NCB) * MB_ROWS;
    float um3 = (t0 - 3 >= bs) ? bf2f(Ub[(size_t)(t0 - 3) * DINNER + ch]) : 0.f;
    float um2 = (t0 - 2 >= bs) ? bf2f(Ub[(size_t)(t0 - 2) * DINNER + ch]) : 0.f;
    float um1 = (t0 - 1 >= bs) ? bf2f(Ub[(size_t)(t0 - 1) * DINNER + ch]) : 0.f;
    __syncthreads();

    float hst[DSTATE] = {};
    for (int t = 0; t < LC; t++) {
        float u0 = bf2f(Ub[(size_t)(t0 + t) * DINNER + ch]);
        float up = fmaf(w3, u0, fmaf(w2, um1, fmaf(w1, um2, fmaf(w0, um3, bia))));
        um3 = um2; um2 = um1; um1 = u0;
        #pragma unroll
        for (int n = 0; n < DSTATE; n++)
            hst[n] = fmaf(hst[n], sdA[t][n], up * sdB[t][n]);
    }
    float* hl = hloc + (((size_t)c * NH + h) * PH + pidx) * DSTATE;
    #pragma unroll
    for (int n = 0; n < DSTATE; n++) hl[n] = hst[n];

    if (pidx < DSTATE) {
        float pr = 1.f;
        for (int t = 0; t < LC; t++) pr *= sdA[t][pidx];
        Pc[((size_t)c * NH + h) * DSTATE + pidx] = pr;
    }
}

// ---------------- scan phase 2: serial carry across chunks (per batch) ----------------
__global__ __launch_bounds__(256) void scan_carry(const float* __restrict__ hloc,
                                                  const float* __restrict__ Pc,
                                                  float* __restrict__ Hent) {
    int g = blockIdx.x * 256 + threadIdx.x;    // nb*32768 threads
    int b = g >> 15;
    int r = g & 32767;
    int h = r >> 12;
    int inner = r & 4095;
    int n = r & 15;
    float carry = 0.f;
    for (int i = 0; i < NCB; i++) {
        int c = b * NCB + i;
        size_t idx = ((size_t)c * NH + h) * (PH * DSTATE) + inner;
        Hent[idx] = carry;
        carry = fmaf(Pc[((size_t)c * NH + h) * DSTATE + n], carry, hloc[idx]);
    }
}

// ---------------- scan phase 3: fused conv + re-run chunk + skip + silu gate -> bf16 ----------------
__global__ __launch_bounds__(256) void scan_out(const ushort* __restrict__ Zb,
                                                const ushort* __restrict__ Ub,
                                                ushort* __restrict__ Yb,
                                                const float* __restrict__ DBC,
                                                const float* __restrict__ dt_,
                                                const float* __restrict__ dA_,
                                                const float* __restrict__ cw,
                                                const float* __restrict__ cb,
                                                const float* __restrict__ Dskip,
                                                const float* __restrict__ Hent) {
    const int c = blockIdx.x, h = blockIdx.y;
    const int pidx = threadIdx.x;
    const int ch = h * PH + pidx;
    const int t0 = c * LC;
    __shared__ float sdA[LC][DSTATE];
    __shared__ float sdB[LC][DSTATE];
    __shared__ float sC [LC][DSTATE];
    const int st = pidx >> 4, sn = pidx & 15;
    #pragma unroll
    for (int j = 0; j < 4; j++) {
        int tt = st + j * 16;
        size_t trow = (size_t)(t0 + tt);
        float dv = dt_[trow * NH + h];
        sdA[tt][sn] = dA_[(trow * NH + h) * DSTATE + sn];
        sdB[tt][sn] = dv * DBC[trow * 320 + 64 + h * DSTATE + sn];
        sC [tt][sn] =      DBC[trow * 320 + 192 + h * DSTATE + sn];
    }
    const float w0 = cw[ch * 4], w1 = cw[ch * 4 + 1], w2 = cw[ch * 4 + 2], w3 = cw[ch * 4 + 3];
    const float bia = cb[ch];
    const int bs = (c / NCB) * MB_ROWS;
    float um3 = (t0 - 3 >= bs) ? bf2f(Ub[(size_t)(t0 - 3) * DINNER + ch]) : 0.f;
    float um2 = (t0 - 2 >= bs) ? bf2f(Ub[(size_t)(t0 - 2) * DINNER + ch]) : 0.f;
    float um1 = (t0 - 1 >= bs) ? bf2f(Ub[(size_t)(t0 - 1) * DINNER + ch]) : 0.f;
    const float dsk = Dskip[ch];
    float hst[DSTATE];
    const float* he = Hent + (((size_t)c * NH + h) * PH + pidx) * DSTATE;
    #pragma unroll
    for (int n = 0; n < DSTATE; n++) hst[n] = he[n];
    __syncthreads();

    for (int t = 0; t < LC; t++) {
        size_t off = (size_t)(t0 + t) * DINNER + ch;
        float u0 = bf2f(Ub[off]);
        float up = fmaf(w3, u0, fmaf(w2, um1, fmaf(w1, um2, fmaf(w0, um3, bia))));
        um3 = um2; um2 = um1; um1 = u0;
        float a0 = 0.f, a1 = 0.f, a2 = 0.f, a3 = 0.f;
        #pragma unroll
        for (int n = 0; n < 4; n++) {
            hst[n +  0] = fmaf(hst[n +  0], sdA[t][n +  0], up * sdB[t][n +  0]);
            hst[n +  4] = fmaf(hst[n +  4], sdA[t][n +  4], up * sdB[t][n +  4]);
            hst[n +  8] = fmaf(hst[n +  8], sdA[t][n +  8], up * sdB[t][n +  8]);
            hst[n + 12] = fmaf(hst[n + 12], sdA[t][n + 12], up * sdB[t][n + 12]);
            a0 = fmaf(hst[n +  0], sC[t][n +  0], a0);
            a1 = fmaf(hst[n +  4], sC[t][n +  4], a1);
            a2 = fmaf(hst[n +  8], sC[t][n +  8], a2);
            a3 = fmaf(hst[n + 12], sC[t][n + 12], a3);
        }
        float yv = ((a0 + a1) + (a2 + a3)) + dsk * up;
        float zv = bf2f(Zb[off]);
        float sil = zv / (1.f + expf(-zv));
        Yb[off] = f2bf(yv * sil);
    }
}

// ---------------- RMSNorm (bf16 in), bf16 output ----------------
__global__ __launch_bounds__(256) void rmsnorm_bf(const ushort* __restrict__ Yb,
                                                  const float* __restrict__ norm_w,
                                                  ushort* __restrict__ Gb) {
    const int row = blockIdx.x;
    const ushort* r = Yb + (size_t)row * DINNER;
    const int c0 = threadIdx.x * 8;
    uint4 packed = *(const uint4*)(r + c0);
    float v[8];
    v[0] = bf2f((ushort)(packed.x & 0xffff)); v[1] = bf2f((ushort)(packed.x >> 16));
    v[2] = bf2f((ushort)(packed.y & 0xffff)); v[3] = bf2f((ushort)(packed.y >> 16));
    v[4] = bf2f((ushort)(packed.z & 0xffff)); v[5] = bf2f((ushort)(packed.z >> 16));
    v[6] = bf2f((ushort)(packed.w & 0xffff)); v[7] = bf2f((ushort)(packed.w >> 16));
    float ss = 0.f;
    #pragma unroll
    for (int i = 0; i < 8; i++) ss = fmaf(v[i], v[i], ss);
    #pragma unroll
    for (int off = 32; off > 0; off >>= 1) ss += __shfl_down(ss, off);
    __shared__ float red[4];
    if ((threadIdx.x & 63) == 0) red[threadIdx.x >> 6] = ss;
    __syncthreads();
    float tot = red[0] + red[1] + red[2] + red[3];
    float inv = rsqrtf(tot / (float)DINNER + 1e-6f);
    float4 w0 = *(const float4*)(norm_w + c0);
    float4 w1 = *(const float4*)(norm_w + c0 + 4);
    uint4 o;
    o.x = cvt2bf(v[0] * inv * w0.x, v[1] * inv * w0.y);
    o.y = cvt2bf(v[2] * inv * w0.z, v[3] * inv * w0.w);
    o.z = cvt2bf(v[4] * inv * w1.x, v[5] * inv * w1.y);
    o.w = cvt2bf(v[6] * inv * w1.z, v[7] * inv * w1.w);
    *(uint4*)(Gb + (size_t)row * DINNER + c0) = o;
}

// ---------------- workspace layout ----------------
struct Lay {
    float *DBC, *DT, *DA, *PC, *HLOC, *HENT;
    ushort *YB, *ZB, *UB, *XBF, *WB;
    size_t total;
};
static Lay mk_layout(char* base, int Mr) {
    size_t o = 0;
    auto take = [&](size_t bytes) { char* p = base + o; o = (o + bytes + 255) & ~(size_t)255; return p; };
    Lay l;
    l.YB   = (ushort*)take((size_t)Mr * 2048 * 2);
    l.DBC  = (float*) take((size_t)Mr * 320 * 4);
    l.DT   = (float*) take((size_t)Mr * 8 * 4);
    l.DA   = (float*) take((size_t)Mr * 128 * 4);
    l.PC   = (float*) take((size_t)(Mr / 64) * NH * DSTATE * 4);
    l.HLOC = (float*) take((size_t)Mr * 512 * 4);
    l.HENT = (float*) take((size_t)Mr * 512 * 4);
    l.ZB   = (ushort*)take((size_t)Mr * 2048 * 2);
    l.UB   = (ushort*)take((size_t)Mr * 2048 * 2);
    l.XBF  = (ushort*)take((size_t)8192 * 1024 * 2);
    l.WB   = (ushort*)take(((size_t)NPAD * 1024 + (size_t)2048 * 1024 + (size_t)1024 * 2048) * 2);
    l.total = o;
    return l;
}

extern "C" void kernel_launch(void* const* d_in, const int* in_sizes, int n_in,
                              void* d_out, int out_size, void* d_ws, size_t ws_size,
                              hipStream_t stream) {
    const float* x       = (const float*)d_in[0];
    const float* W_in    = (const float*)d_in[1];
    const float* W_dt    = (const float*)d_in[2];
    const float* conv_w  = (const float*)d_in[3];
    const float* conv_b  = (const float*)d_in[4];
    const float* A_log   = (const float*)d_in[5];
    const float* Dskip   = (const float*)d_in[6];
    const float* dt_bias = (const float*)d_in[7];
    const float* norm_w  = (const float*)d_in[8];
    const float* W_out   = (const float*)d_in[9];
    const float* W_res   = (const float*)d_in[10];
    float* out = (float*)d_out;

    Lay probe = mk_layout(nullptr, 2 * MB_ROWS);
    const bool fat = ws_size >= probe.total;
    const int Mr = fat ? 2 * MB_ROWS : MB_ROWS;
    const int npass = fat ? 1 : 2;
    const int nbc = fat ? 2 : 1;
    Lay l = mk_layout((char*)d_ws, Mr);

    ushort* winb = l.WB;
    ushort* wrsb = winb + (size_t)NPAD * 1024;
    ushort* wotb = wrsb + (size_t)2048 * 1024;
    ushort* Gb   = l.ZB;                  // Z dead after scan_out; reuse for g

    cvt_weights<<<4288, 256, 0, stream>>>(W_in, W_res, W_out, l.WB);
    cvt_bf<<<(2 * MB_ROWS * DMODEL / 8) / 256, 256, 0, stream>>>(x, l.XBF);

    for (int b = 0; b < npass; b++) {
        const ushort* xb = l.XBF + (size_t)b * MB_ROWS * DMODEL;
        float* outb = out + (size_t)b * MB_ROWS * DMODEL;
        const int nty = Mr / 256;

        // 1. in-projection -> Zb(bf16) | Ub(bf16) | DBC(fp32)
        gemm_p<2><<<35 * nty, 512, 0, stream>>>(xb, winb, nullptr, nullptr, l.ZB, l.UB, l.DBC, 35, DMODEL, 0);
        // 2. dt head + dA table
        dt_kernel<<<(Mr * NH) / 256, 256, 0, stream>>>(l.DBC, W_dt, dt_bias, A_log, l.DT, l.DA);
        // 3. chunk-parallel scan with fused causal conv; gated y -> Yb (bf16)
        scan_local<<<dim3(Mr / LC, NH), 256, 0, stream>>>(l.UB, l.DBC, l.DT, l.DA, conv_w, conv_b, l.HLOC, l.PC);
        scan_carry<<<nbc * 128, 256, 0, stream>>>(l.HLOC, l.PC, l.HENT);
        scan_out<<<dim3(Mr / LC, NH), 256, 0, stream>>>(l.ZB, l.UB, l.YB, l.DBC, l.DT, l.DA,
                                                        conv_w, conv_b, Dskip, l.HENT);
        // 4. residual GEMM accumulate (bf16 RMW): Yb += x @ W_res^T
        gemm_p<1><<<16 * nty, 512, 0, stream>>>(xb, wrsb, nullptr, l.YB, nullptr, nullptr, nullptr, 16, DMODEL, DINNER);
        // 5. RMSNorm (bf16 in) -> bf16 g
        rmsnorm_bf<<<Mr, 256, 0, stream>>>(l.YB, norm_w, Gb);
        // 6. out-projection: out = g @ W_out^T (fp32 out)
        gemm_p<0><<<8 * nty, 512, 0, stream>>>(Gb, wotb, outb, nullptr, nullptr, nullptr, nullptr, 8, DINNER, DMODEL);
    }
}